// Round 15
// baseline (1178.338 us; speedup 1.0000x reference)
//
#include <hip/hip_runtime.h>
#include <math.h>

// ---------------- problem constants ----------------
#define NS 612
#define NECOL 216
#define BATCH 32
#define TLEN 2048
#define ROWW 1024                // floats per permuted emission row (4 KB)
#define CE 2.7182818284590452f

// ---------------- ws layout (float offsets) ----------------
#define O_AV0 0
#define O_AV1 128
#define O_BV0 256
#define O_BV1 384
#define O_IZ3 512
#define O_SC  640                // [0]=wk [1]=A00 [2]=A01
#define O_PIP 768                // [1024] permuted softmax(init)
#define O_ET  2048               // [216*1024] permuted E^T rows

typedef float f32x4 __attribute__((ext_vector_type(4)));
typedef int   i32x2 __attribute__((ext_vector_type(2)));

// slot map: lane L holds pair i=2L,2L+1 in 13 floats at row+L*64B
//  f0..f3 = c4e,c5e,c6e,i8e   f4..f7 = i9e,i10e,c4o,c5o
//  f8..f11 = c6o,i8o,i9o,i10o  f12 = special-Et
// specials: {0,1,2,3}->lanes 60..63, {307}->lane 51, {611}->lane 52
__device__ __forceinline__ int eslot(int s) {
  if (s >= 4 && s <= 306)  { int i = (s - 4) / 3,  r = (s - 4) % 3;
    return (i >> 1) * 16 + (i & 1) * 6 + r; }
  if (s >= 308 && s <= 610){ int i = (s - 308) / 3, r = (s - 308) % 3;
    return (i >> 1) * 16 + (i & 1) * 6 + 3 + r; }
  if (s <= 3)   return (60 + s) * 16 + 12;
  if (s == 307) return 51 * 16 + 12;
  return 52 * 16 + 12;   // s == 611
}

// ---------------- DPP helpers ----------------
#define DPPF(x, ctrl, rm) __int_as_float(__builtin_amdgcn_update_dpp(0, __float_as_int(x), (ctrl), (rm), 0xf, true))

__device__ __forceinline__ float scan_plain(float x) {
  x += DPPF(x, 0x111, 0xf);
  x += DPPF(x, 0x112, 0xf);
  x += DPPF(x, 0x114, 0xf);
  x += DPPF(x, 0x118, 0xf);
  x += DPPF(x, 0x142, 0xa);
  x += DPPF(x, 0x143, 0xc);
  return x;
}
__device__ __forceinline__ float wshr1(float x) { return DPPF(x, 0x138, 0xf); }   // dst[l]=src[l-1], dst[0]=0
__device__ __forceinline__ float ror1(float x)  { return DPPF(x, 0x13C, 0xf); }   // dst[l]=src[l-1], dst[0]=src[63]
__device__ __forceinline__ float rdl(float x, int l) {
  return __int_as_float(__builtin_amdgcn_readlane(__float_as_int(x), l));
}

// ---------------- prep kernels (unchanged math, verified) ----------------
__global__ void k_prep(const float* __restrict__ w, float* __restrict__ ws) {
  __shared__ float Gs[101];
  int tid = threadIdx.x;                  // 128
  float wk = w[304];
  if (tid >= 1 && tid <= 100) {
    float p = wk;
    for (int k = 0; k < tid; ++k) p *= wk;
    Gs[tid] = expf(1.f - p);
  }
  if (tid == 0) {
    Gs[0] = 0.f;
    ws[O_SC + 0] = wk;
    float Z0 = expf(1.f - w[0]) + expf(w[0]);
    ws[O_SC + 1] = expf(1.f - w[0]) / Z0;
    ws[O_SC + 2] = expf(w[0]) / Z0;
  }
  __syncthreads();
  if (tid <= 100) {
    float em = expf(w[tid < 100 ? 1 + tid : 202]);
    float ei = expf(w[101 + tid]);
    float z = em + ei;
    for (int d = 1; d <= 100 - tid; ++d) z += Gs[d];
    float ex = expf(w[203 + tid]);
    float es = expf(1.f - w[203 + tid]);
    float z310 = ex + es;
    ws[O_AV0 + tid] = em / z;
    ws[O_BV0 + tid] = ei / z;
    ws[O_AV1 + tid] = ex / z310;
    ws[O_BV1 + tid] = es / z310;
    ws[O_IZ3 + tid] = 1.f / z;
  }
}

__global__ void k_zr(float* __restrict__ ws) {
  float* row = ws + O_ET + (size_t)blockIdx.x * ROWW;
  for (int i = threadIdx.x; i < ROWW; i += 256) row[i] = 0.f;
}

__global__ void k_et(const float* __restrict__ ek, float* __restrict__ ws) {
  float* Etp = ws + O_ET;
  int s = blockIdx.x;
  int lane = threadIdx.x;                 // 64
  int sl = eslot(s);
  float x[4]; float m = -1e30f;
  #pragma unroll
  for (int k = 0; k < 4; ++k) {
    int c = lane + 64 * k;
    x[k] = (c < NECOL) ? ek[s * NECOL + c] : -1e30f;
    m = fmaxf(m, x[k]);
  }
  #pragma unroll
  for (int o = 32; o; o >>= 1) m = fmaxf(m, __shfl_xor(m, o, 64));
  float e[4]; float sum = 0.f;
  #pragma unroll
  for (int k = 0; k < 4; ++k) {
    int c = lane + 64 * k;
    e[k] = (c < NECOL) ? expf(x[k] - m) : 0.f;
    sum += e[k];
  }
  #pragma unroll
  for (int o = 32; o; o >>= 1) sum += __shfl_xor(sum, o, 64);
  float inv = 1.f / sum;
  #pragma unroll
  for (int k = 0; k < 4; ++k) {
    int c = lane + 64 * k;
    if (c < NECOL) Etp[(size_t)c * ROWW + sl] = e[k] * inv;
  }
}

__global__ void k_pi(const float* __restrict__ ik, float* __restrict__ ws) {
  float* pip = ws + O_PIP;
  __shared__ float wm[10], wsm[10];
  int tid = threadIdx.x;                  // 640
  for (int i = tid; i < ROWW; i += 640) pip[i] = 0.f;
  __syncthreads();
  int lane = tid & 63, wid = tid >> 6;
  float x = (tid < NS) ? ik[tid] : -1e30f;
  float m = x;
  #pragma unroll
  for (int o = 32; o; o >>= 1) m = fmaxf(m, __shfl_xor(m, o, 64));
  if (lane == 0) wm[wid] = m;
  __syncthreads();
  float mm = wm[0];
  #pragma unroll
  for (int k = 1; k < 10; ++k) mm = fmaxf(mm, wm[k]);
  float e = (tid < NS) ? expf(x - mm) : 0.f;
  float sacc = e;
  #pragma unroll
  for (int o = 32; o; o >>= 1) sacc += __shfl_xor(sacc, o, 64);
  if (lane == 0) wsm[wid] = sacc;
  __syncthreads();
  float ss = 0.f;
  #pragma unroll
  for (int k = 0; k < 10; ++k) ss += wsm[k];
  if (tid < NS) pip[eslot(tid)] = e / ss;
}

// ---------------- main: 8 waves/block (2 per SIMD), one SEQUENCE per wave ---
// TLP: two independent waves per SIMD interleave issue, filling each other's
// VALU/DPP latency stalls. Per-wave code = r13 verified. ids base is forced
// into SGPRs via per-half readfirstlane (wave-uniform, r14 compile fix).
__global__ __launch_bounds__(512, 2) void k_main(const int* __restrict__ ids,
                                                 const float* __restrict__ ws,
                                                 float* __restrict__ out) {
  const int L = threadIdx.x & 63;
  const int wv = threadIdx.x >> 6;              // wave id 0..7
  const int bseq = blockIdx.x * 8 + wv;         // sequence index 0..31
  const int* idsb = ids + bseq * TLEN;
  const float* Etp = ws + O_ET;
  const float* pip = ws + O_PIP;
  const unsigned long long Et64 = (unsigned long long)Etp;
  // wave-uniform ids base -> SGPR pair (readfirstlane halves)
  unsigned long long idsv = (unsigned long long)idsb;
  unsigned int ids_lo = __builtin_amdgcn_readfirstlane((unsigned int)idsv);
  unsigned int ids_hi = __builtin_amdgcn_readfirstlane((unsigned int)(idsv >> 32));
  const unsigned long long ids64 = ((unsigned long long)ids_hi << 32) | ids_lo;
  const int voff = L << 6;

  // per-lane coefficients
  int ie = 2 * L;     if (ie > 100) ie = 100;
  int io = 2 * L + 1; if (io > 100) io = 100;
  float AV0e = ws[O_AV0 + ie], AV1e = ws[O_AV1 + ie];
  float BV0e = ws[O_BV0 + ie], BV1e = ws[O_BV1 + ie];
  float AV0o = ws[O_AV0 + io], AV1o = ws[O_AV1 + io];
  float BV0o = ws[O_BV0 + io], BV1o = ws[O_BV1 + io];
  float izeCE = ((2 * L <= 99)     ? ws[O_IZ3 + 2 * L]     : 0.f) * CE;
  float izoCE = ((2 * L + 1 <= 99) ? ws[O_IZ3 + 2 * L + 1] : 0.f) * CE;
  float wk  = ws[O_SC + 0], A00 = ws[O_SC + 1], A01 = ws[O_SC + 2];

  // specials: lanes 60..63 = {0,1,2,3}; lane 51 = 307; lane 52 = 611
  float k0 = 0.f, k1 = 0.f, kx = 0.f;
  if (L == 61) k0 = A01;
  else if (L == 62 || L == 63) k0 = 1.f;
  else if (L == 52) k0 = 0.5f;
  if (L == 60) k1 = A00;
  else if (L == 51) { k1 = 0.5f; kx = 1.f; }
  else if (L == 52) k1 = 1.f;
  const bool isL0 = (L == 0);

  const float sk1 = 1.f - wk;
  const float r2 = wk * wk;
  const float q1 = r2, q2 = r2 * r2;

  // ---- t = 0: beta = pi * Et[obs0] ----
  int ob0 = __builtin_amdgcn_readfirstlane(idsb[0]);
  const float* R0 = Etp + (size_t)ob0 * ROWW;
  f32x4 p0 = *(const f32x4*)(pip + L * 16);
  f32x4 p1 = *(const f32x4*)(pip + L * 16 + 4);
  f32x4 p2 = *(const f32x4*)(pip + L * 16 + 8);
  float p3 = pip[L * 16 + 12];
  f32x4 e0 = *(const f32x4*)(R0 + L * 16);
  f32x4 e1 = *(const f32x4*)(R0 + L * 16 + 4);
  f32x4 e2 = *(const f32x4*)(R0 + L * 16 + 8);
  float e3 = R0[L * 16 + 12];

  float c4e = p0.x * e0.x, c5e = p0.y * e0.y, c6e = p0.z * e0.z, i8e = p0.w * e0.w;
  float i9e = p1.x * e1.x, i10e = p1.y * e1.y, c4o = p1.z * e1.z, c5o = p1.w * e1.w;
  float c6o = p2.x * e2.x, i8o = p2.y * e2.y, i9o = p2.z * e2.z, i10o = p2.w * e2.w;
  float spv = p3 * e3;

  // initial md + scans (feed D at t=1); live: Sp, Tp, mdo
  float Sp, Tp, mdo;
  {
    float sprd0 = ror1(spv);
    float pme = isL0 ? sprd0 : ror1(c6o);
    float mde = pme * izeCE;
    mdo = c6e * izoCE;
    Sp = scan_plain(mde + mdo);
    float v1 = fmaf(wk, mde, mdo);
    float t1 = wshr1(v1), t2 = wshr1(t1);
    Tp = fmaf(q2, t2, fmaf(q1, t1, v1));
  }

  int e_acc = 0;

  // ---- single step (prologue only) ----
#define STEP_BODY(B0, B1, B2, B3) do { \
    float De = fmaf(-r2, wshr1(Tp), wshr1(Sp)); \
    float Do = fmaf(-wk, Tp, Sp); Do = fmaf(-sk1, mdo, Do); \
    float exc  = ror1(c6e); \
    float sprd = ror1(spv); \
    float pve = isL0 ? sprd : ror1(c6o); \
    float pvo = c6e; \
    float t4e = fmaf(AV0e, pve, fmaf(AV1e, i10e, De)) * (B0).x; \
    float t5e = c4e * (B0).y; \
    float t6e = c5e * (B0).z; \
    float t8e = fmaf(BV0e, pve, BV1e * i10e) * (B0).w; \
    float t9e = i8e * (B1).x; \
    float tXe = i9e * (B1).y; \
    float t4o = fmaf(AV0o, pvo, fmaf(AV1o, i10o, Do)) * (B1).z; \
    float t5o = c4o * (B1).w; \
    float t6o = c5o * (B2).x; \
    float t8o = fmaf(BV0o, pvo, BV1o * i10o) * (B2).y; \
    float t9o = i8o * (B2).z; \
    float tXo = i9o * (B2).w; \
    float nsp = fmaf(kx, exc, fmaf(k0, sprd, k1 * spv)) * (B3); \
    c4e = t4e; c5e = t5e; c6e = t6e; i8e = t8e; i9e = t9e; i10e = tXe; \
    c4o = t4o; c5o = t5o; c6o = t6o; i8o = t8o; i9o = t9o; i10o = tXo; \
    spv = nsp; \
    float sprdn = ror1(spv); \
    float pmn = isL0 ? sprdn : ror1(c6o); \
    float mde = pmn * izeCE; \
    mdo = c6e * izoCE; \
    Sp = scan_plain(mde + mdo); \
    float v1 = fmaf(wk, mde, mdo); \
    float t1 = wshr1(v1), t2 = wshr1(t1); \
    Tp = fmaf(q2, t2, fmaf(q1, t1, v1)); \
  } while (0)

  // ---- fused 3 steps (r13 verified) ----
#define FUSE3(R1a,R1b,R1c,R1d, R2a,R2b,R2c,R2d, R3a,R3b,R3c,R3d) do { \
    float De1 = fmaf(-r2, wshr1(Tp), wshr1(Sp)); \
    float Do1 = fmaf(-wk, Tp, Sp); Do1 = fmaf(-sk1, mdo, Do1); \
    float exc1  = ror1(c6e); \
    float sprd1 = ror1(spv); \
    float pve1 = isL0 ? sprd1 : ror1(c6o); \
    float a4e = fmaf(AV0e, pve1, fmaf(AV1e, i10e, De1)) * (R1a).x; \
    float a5e = c4e * (R1a).y; \
    float a6e = c5e * (R1a).z; \
    float a8e = fmaf(BV0e, pve1, BV1e * i10e) * (R1a).w; \
    float a9e = i8e * (R1b).x; \
    float aXe = i9e * (R1b).y; \
    float a4o = fmaf(AV0o, c6e, fmaf(AV1o, i10o, Do1)) * (R1b).z; \
    float a5o = c4o * (R1b).w; \
    float a6o = c5o * (R1c).x; \
    float a8o = fmaf(BV0o, c6e, BV1o * i10o) * (R1c).y; \
    float a9o = i8o * (R1c).z; \
    float aXo = i9o * (R1c).w; \
    float asp = fmaf(kx, exc1, fmaf(k0, sprd1, k1 * spv)) * (R1d); \
    float b5e = a4e * (R2a).y; \
    float b6e = a5e * (R2a).z; \
    float b9e = a8e * (R2b).x; \
    float bXe = a9e * (R2b).y; \
    float b5o = a4o * (R2b).w; \
    float b6o = a5o * (R2c).x; \
    float b9o = a8o * (R2c).z; \
    float bXo = a9o * (R2c).w; \
    float exc2  = ror1(a6e); \
    float sprd2 = ror1(asp); \
    float bsp = fmaf(kx, exc2, fmaf(k0, sprd2, k1 * asp)) * (R2d); \
    float pve2 = isL0 ? sprd2 : ror1(a6o); \
    float b8e = fmaf(BV0e, pve2, BV1e * aXe) * (R2a).w; \
    float b8o = fmaf(BV0o, a6e, BV1o * aXo) * (R2c).y; \
    float md1e = pve2 * izeCE; \
    float md1o = a6e * izoCE; \
    float c6e3 = b5e * (R3a).z; \
    float c6o3 = b5o * (R3c).x; \
    float c9e3 = b8e * (R3b).x; \
    float cXe3 = b9e * (R3b).y; \
    float c9o3 = b8o * (R3c).z; \
    float cXo3 = b9o * (R3c).w; \
    float exc3  = ror1(b6e); \
    float sprd3 = ror1(bsp); \
    float csp = fmaf(kx, exc3, fmaf(k0, sprd3, k1 * bsp)) * (R3d); \
    float pve3 = isL0 ? sprd3 : ror1(b6o); \
    float md2e = pve3 * izeCE; \
    float md2o = b6e * izoCE; \
    float c8e3 = fmaf(BV0e, pve3, BV1e * bXe) * (R3a).w; \
    float c8o3 = fmaf(BV0o, b6e, BV1o * bXo) * (R3c).y; \
    float sprd4 = ror1(csp); \
    float pm3 = isL0 ? sprd4 : ror1(c6o3); \
    float md3e = pm3 * izeCE; \
    float md3o = c6e3 * izoCE; \
    float S1 = md1e + md1o, T1v = fmaf(wk, md1e, md1o); \
    float S2 = md2e + md2o, T2v = fmaf(wk, md2e, md2o); \
    float S3 = md3e + md3o, T3v = fmaf(wk, md3e, md3o); \
    S1 += DPPF(S1, 0x111, 0xf); S2 += DPPF(S2, 0x111, 0xf); S3 += DPPF(S3, 0x111, 0xf); \
    float t1a = wshr1(T1v), t2a = wshr1(T2v), t3a = wshr1(T3v); \
    S1 += DPPF(S1, 0x112, 0xf); S2 += DPPF(S2, 0x112, 0xf); S3 += DPPF(S3, 0x112, 0xf); \
    float t1b = wshr1(t1a), t2b = wshr1(t2a), t3b = wshr1(t3a); \
    S1 += DPPF(S1, 0x114, 0xf); S2 += DPPF(S2, 0x114, 0xf); S3 += DPPF(S3, 0x114, 0xf); \
    float T1 = fmaf(q2, t1b, fmaf(q1, t1a, T1v)); \
    float T2 = fmaf(q2, t2b, fmaf(q1, t2a, T2v)); \
    float T3 = fmaf(q2, t3b, fmaf(q1, t3a, T3v)); \
    S1 += DPPF(S1, 0x118, 0xf); S2 += DPPF(S2, 0x118, 0xf); S3 += DPPF(S3, 0x118, 0xf); \
    S1 += DPPF(S1, 0x142, 0xa); S2 += DPPF(S2, 0x142, 0xa); S3 += DPPF(S3, 0x142, 0xa); \
    S1 += DPPF(S1, 0x143, 0xc); S2 += DPPF(S2, 0x143, 0xc); S3 += DPPF(S3, 0x143, 0xc); \
    float De2 = fmaf(-r2, wshr1(T1), wshr1(S1)); \
    float Do2 = fmaf(-wk, T1, S1); Do2 = fmaf(-sk1, md1o, Do2); \
    float b4e = fmaf(AV0e, pve2, fmaf(AV1e, aXe, De2)) * (R2a).x; \
    float b4o = fmaf(AV0o, a6e, fmaf(AV1o, aXo, Do2)) * (R2b).z; \
    float c5e3 = b4e * (R3a).y; \
    float c5o3 = b4o * (R3b).w; \
    float De3 = fmaf(-r2, wshr1(T2), wshr1(S2)); \
    float Do3 = fmaf(-wk, T2, S2); Do3 = fmaf(-sk1, md2o, Do3); \
    float c4e3 = fmaf(AV0e, pve3, fmaf(AV1e, bXe, De3)) * (R3a).x; \
    float c4o3 = fmaf(AV0o, b6e, fmaf(AV1o, bXo, Do3)) * (R3b).z; \
    c4e = c4e3; c5e = c5e3; c6e = c6e3; i8e = c8e3; i9e = c9e3; i10e = cXe3; \
    c4o = c4o3; c5o = c5o3; c6o = c6o3; i8o = c8o3; i9o = c9o3; i10o = cXo3; \
    spv = csp; \
    Sp = S3; Tp = T3; mdo = md3o; \
  } while (0)

#define RESCALE() do { \
    float prr = ((c4e + c5e) + (c6e + i8e)) + ((i9e + i10e) + (c4o + c5o)) \
              + ((c6o + i8o) + (i9o + i10o)) + spv; \
    float ssum = rdl(scan_plain(prr), 63); \
    int exq = ((__float_as_int(ssum) >> 23) & 255) - 127; \
    e_acc += exq; \
    float scq = __int_as_float((127 - exq) << 23); \
    c4e *= scq; c5e *= scq; c6e *= scq; i8e *= scq; i9e *= scq; i10e *= scq; \
    c4o *= scq; c5o *= scq; c6o *= scq; i8o *= scq; i9o *= scq; i10o *= scq; \
    spv *= scq; \
    mdo *= scq; Sp *= scq; Tp *= scq; \
  } while (0)

  // ---- asm load primitives (r8-proven, verbatim) ----
#define GLD4(dst, base, off) \
  asm volatile("global_load_dwordx4 %0, %1, %2 offset:" #off \
               : "=v"(dst) : "v"(voff), "s"(base))
#define GLD1(dst, base, off) \
  asm volatile("global_load_dword %0, %1, %2 offset:" #off \
               : "=v"(dst) : "v"(voff), "s"(base))
#define GLD2(dst, base, vo, off) \
  asm volatile("global_load_dwordx2 %0, %1, %2 offset:" #off \
               : "=v"(dst) : "v"(vo), "s"(base))

#define LOADROW(P, obsv) do { \
    unsigned int _oc = (unsigned int)__builtin_amdgcn_readfirstlane(obsv); \
    unsigned long long _ba = Et64 + ((unsigned long long)_oc << 12); \
    GLD4(P##0, _ba, 0); \
    GLD4(P##1, _ba, 16); \
    GLD4(P##2, _ba, 32); \
    GLD1(P##3, _ba, 48); \
  } while (0)

#define LOADOBS(O, tstart) do { \
    int _ts = (tstart); if (_ts > TLEN - 6) _ts = TLEN - 6; \
    int _vo = _ts * 4; \
    GLD2(O##0, ids64, _vo, 0); \
    GLD2(O##1, ids64, _vo, 8); \
    GLD2(O##2, ids64, _vo, 16); \
  } while (0)

  // ---- prologue: t = 1..7 synchronous ----
  for (int t = 1; t <= 7; ++t) {
    int obp = idsb[t];
    const float* Rx = Etp + (size_t)__builtin_amdgcn_readfirstlane(obp) * ROWW;
    f32x4 P0 = *(const f32x4*)(Rx + L * 16);
    f32x4 P1 = *(const f32x4*)(Rx + L * 16 + 4);
    f32x4 P2 = *(const f32x4*)(Rx + L * 16 + 8);
    float P3 = Rx[L * 16 + 12];
    STEP_BODY(P0, P1, P2, P3);
  }
  RESCALE();

  // ---- pipeline buffers (r8 naming, verbatim) ----
  f32x4 Ar00, Ar01, Ar02; float Ar03;
  f32x4 Ar10, Ar11, Ar12; float Ar13;
  f32x4 Ar20, Ar21, Ar22; float Ar23;
  f32x4 Ar30, Ar31, Ar32; float Ar33;
  f32x4 Ar40, Ar41, Ar42; float Ar43;
  f32x4 Ar50, Ar51, Ar52; float Ar53;
  f32x4 Br00, Br01, Br02; float Br03;
  f32x4 Br10, Br11, Br12; float Br13;
  f32x4 Br20, Br21, Br22; float Br23;
  f32x4 Br30, Br31, Br32; float Br33;
  f32x4 Br40, Br41, Br42; float Br43;
  f32x4 Br50, Br51, Br52; float Br53;
  i32x2 OA0, OA1, OA2, OB0, OB1, OB2;

  LOADOBS(OA, 8);
  asm volatile("s_waitcnt vmcnt(0)" ::: "memory");
  __builtin_amdgcn_sched_barrier(0);
  LOADROW(Ar0, OA0.x);
  LOADROW(Ar1, OA0.y);
  LOADROW(Ar2, OA1.x);
  LOADROW(Ar3, OA1.y);
  LOADROW(Ar4, OA2.x);
  LOADROW(Ar5, OA2.y);
  LOADOBS(OB, 14);

#define ITER(C, OC, N, ON, gexp) do { \
    asm volatile("s_waitcnt vmcnt(0)" ::: "memory"); \
    __builtin_amdgcn_sched_barrier(0); \
    LOADROW(N##r0, (OC##0).x); \
    LOADROW(N##r1, (OC##0).y); \
    LOADROW(N##r2, (OC##1).x); \
    LOADROW(N##r3, (OC##1).y); \
    LOADROW(N##r4, (OC##2).x); \
    LOADROW(N##r5, (OC##2).y); \
    LOADOBS(ON, 8 + 6 * ((gexp) + 2)); \
    __builtin_amdgcn_sched_barrier(0); \
    FUSE3(C##r00, C##r01, C##r02, C##r03, \
          C##r10, C##r11, C##r12, C##r13, \
          C##r20, C##r21, C##r22, C##r23); \
    FUSE3(C##r30, C##r31, C##r32, C##r33, \
          C##r40, C##r41, C##r42, C##r43, \
          C##r50, C##r51, C##r52, C##r53); \
  } while (0)

  // 340 groups of 6 steps: t = 8 .. 2047; rescale every 12 steps
  for (int g = 0; g < 340; g += 2) {
    ITER(A, OB, B, OA, g);
    ITER(B, OA, A, OB, g + 1);
    RESCALE();
  }

  // ---- final: ll = e_acc*ln2 + log(sum beta_final) ----
  float prr = ((c4e + c5e) + (c6e + i8e)) + ((i9e + i10e) + (c4o + c5o))
            + ((c6o + i8o) + (i9o + i10o)) + spv;
  float ssum_f = rdl(scan_plain(prr), 63);
  double ll = (double)e_acc * 0.6931471805599453 + (double)logf(ssum_f);
  if (L == 0) out[bseq] = (float)ll;

#undef STEP_BODY
#undef FUSE3
#undef RESCALE
#undef GLD4
#undef GLD1
#undef GLD2
#undef LOADROW
#undef LOADOBS
#undef ITER
}

// ---------------- launcher ----------------
extern "C" void kernel_launch(void* const* d_in, const int* in_sizes, int n_in,
                              void* d_out, int out_size, void* d_ws, size_t ws_size,
                              hipStream_t stream) {
  const int*   ids = (const int*)d_in[0];
  const float* w   = (const float*)d_in[1];
  const float* ek  = (const float*)d_in[2];
  const float* ik  = (const float*)d_in[3];
  float* ws  = (float*)d_ws;
  float* out = (float*)d_out;

  k_prep<<<1, 128, 0, stream>>>(w, ws);
  k_zr  <<<NECOL, 256, 0, stream>>>(ws);
  k_pi  <<<1, 640, 0, stream>>>(ik, ws);
  k_et  <<<NS, 64, 0, stream>>>(ek, ws);
  k_main<<<4, 512, 0, stream>>>(ids, ws, out);
}

// Round 17
// 266.620 us; speedup vs baseline: 4.4195x; 4.4195x over previous
//
#include <hip/hip_runtime.h>
#include <math.h>

// ---------------- problem constants ----------------
#define NS 612
#define NECOL 216
#define BATCH 32
#define TLEN 2048
#define ROWW 1024                // floats per permuted emission row (4 KB)
#define CE 2.7182818284590452f

// ---------------- ws layout (float offsets) ----------------
#define O_AV0 0
#define O_AV1 128
#define O_BV0 256
#define O_BV1 384
#define O_IZ3 512
#define O_SC  640                // [0]=wk [1]=A00 [2]=A01
#define O_PIP 768                // [1024] permuted softmax(init)
#define O_ET  2048               // [216*1024] permuted E^T rows

typedef float f32x4 __attribute__((ext_vector_type(4)));
typedef float f32x2 __attribute__((ext_vector_type(2)));
typedef int   i32x2 __attribute__((ext_vector_type(2)));

// PACKED slot map: lane L holds pair i=2L,2L+1 in 13 floats at row+L*64B,
// grouped as e/o pairs for v_pk_* math:
//  f0,f1=c4e,c4o  f2,f3=c5e,c5o  f4,f5=c6e,c6o
//  f6,f7=i8e,i8o  f8,f9=i9e,i9o  f10,f11=i10e,i10o  f12=special-Et
// specials: {0,1,2,3}->lanes 60..63, {307}->lane 51, {611}->lane 52
__device__ __forceinline__ int eslot(int s) {
  if (s >= 4 && s <= 306)  { int i = (s - 4) / 3,  r = (s - 4) % 3;
    return (i >> 1) * 16 + 2 * r + (i & 1); }
  if (s >= 308 && s <= 610){ int i = (s - 308) / 3, r = (s - 308) % 3;
    return (i >> 1) * 16 + 6 + 2 * r + (i & 1); }
  if (s <= 3)   return (60 + s) * 16 + 12;
  if (s == 307) return 51 * 16 + 12;
  return 52 * 16 + 12;   // s == 611
}

// ---------------- DPP / packed helpers ----------------
#define DPPF(x, ctrl, rm) __int_as_float(__builtin_amdgcn_update_dpp(0, __float_as_int(x), (ctrl), (rm), 0xf, true))
#define LO2(v) __builtin_shufflevector((v), (v), 0, 1)
#define HI2(v) __builtin_shufflevector((v), (v), 2, 3)
#define PKF(a, b, c) __builtin_elementwise_fma((a), (b), (c))

__device__ __forceinline__ f32x2 mk2(float a, float b) { f32x2 r; r.x = a; r.y = b; return r; }

__device__ __forceinline__ float scan_plain(float x) {
  x += DPPF(x, 0x111, 0xf);
  x += DPPF(x, 0x112, 0xf);
  x += DPPF(x, 0x114, 0xf);
  x += DPPF(x, 0x118, 0xf);
  x += DPPF(x, 0x142, 0xa);
  x += DPPF(x, 0x143, 0xc);
  return x;
}
__device__ __forceinline__ float wshr1(float x) { return DPPF(x, 0x138, 0xf); }   // dst[l]=src[l-1], dst[0]=0
__device__ __forceinline__ float ror1(float x)  { return DPPF(x, 0x13C, 0xf); }   // dst[l]=src[l-1], dst[0]=src[63]
__device__ __forceinline__ float rdl(float x, int l) {
  return __int_as_float(__builtin_amdgcn_readlane(__float_as_int(x), l));
}

// ---------------- prep kernels (math unchanged, verified) ----------------
__global__ void k_prep(const float* __restrict__ w, float* __restrict__ ws) {
  __shared__ float Gs[101];
  int tid = threadIdx.x;                  // 128
  float wk = w[304];
  if (tid >= 1 && tid <= 100) {
    float p = wk;
    for (int k = 0; k < tid; ++k) p *= wk;
    Gs[tid] = expf(1.f - p);
  }
  if (tid == 0) {
    Gs[0] = 0.f;
    ws[O_SC + 0] = wk;
    float Z0 = expf(1.f - w[0]) + expf(w[0]);
    ws[O_SC + 1] = expf(1.f - w[0]) / Z0;
    ws[O_SC + 2] = expf(w[0]) / Z0;
  }
  __syncthreads();
  if (tid <= 100) {
    float em = expf(w[tid < 100 ? 1 + tid : 202]);
    float ei = expf(w[101 + tid]);
    float z = em + ei;
    for (int d = 1; d <= 100 - tid; ++d) z += Gs[d];
    float ex = expf(w[203 + tid]);
    float es = expf(1.f - w[203 + tid]);
    float z310 = ex + es;
    ws[O_AV0 + tid] = em / z;
    ws[O_BV0 + tid] = ei / z;
    ws[O_AV1 + tid] = ex / z310;
    ws[O_BV1 + tid] = es / z310;
    ws[O_IZ3 + tid] = 1.f / z;
  }
}

__global__ void k_zr(float* __restrict__ ws) {
  float* row = ws + O_ET + (size_t)blockIdx.x * ROWW;
  for (int i = threadIdx.x; i < ROWW; i += 256) row[i] = 0.f;
}

__global__ void k_et(const float* __restrict__ ek, float* __restrict__ ws) {
  float* Etp = ws + O_ET;
  int s = blockIdx.x;
  int lane = threadIdx.x;                 // 64
  int sl = eslot(s);
  float x[4]; float m = -1e30f;
  #pragma unroll
  for (int k = 0; k < 4; ++k) {
    int c = lane + 64 * k;
    x[k] = (c < NECOL) ? ek[s * NECOL + c] : -1e30f;
    m = fmaxf(m, x[k]);
  }
  #pragma unroll
  for (int o = 32; o; o >>= 1) m = fmaxf(m, __shfl_xor(m, o, 64));
  float e[4]; float sum = 0.f;
  #pragma unroll
  for (int k = 0; k < 4; ++k) {
    int c = lane + 64 * k;
    e[k] = (c < NECOL) ? expf(x[k] - m) : 0.f;
    sum += e[k];
  }
  #pragma unroll
  for (int o = 32; o; o >>= 1) sum += __shfl_xor(sum, o, 64);
  float inv = 1.f / sum;
  #pragma unroll
  for (int k = 0; k < 4; ++k) {
    int c = lane + 64 * k;
    if (c < NECOL) Etp[(size_t)c * ROWW + sl] = e[k] * inv;
  }
}

__global__ void k_pi(const float* __restrict__ ik, float* __restrict__ ws) {
  float* pip = ws + O_PIP;
  __shared__ float wm[10], wsm[10];
  int tid = threadIdx.x;                  // 640
  for (int i = tid; i < ROWW; i += 640) pip[i] = 0.f;
  __syncthreads();
  int lane = tid & 63, wid = tid >> 6;
  float x = (tid < NS) ? ik[tid] : -1e30f;
  float m = x;
  #pragma unroll
  for (int o = 32; o; o >>= 1) m = fmaxf(m, __shfl_xor(m, o, 64));
  if (lane == 0) wm[wid] = m;
  __syncthreads();
  float mm = wm[0];
  #pragma unroll
  for (int k = 1; k < 10; ++k) mm = fmaxf(mm, wm[k]);
  float e = (tid < NS) ? expf(x - mm) : 0.f;
  float sacc = e;
  #pragma unroll
  for (int o = 32; o; o >>= 1) sacc += __shfl_xor(sacc, o, 64);
  if (lane == 0) wsm[wid] = sacc;
  __syncthreads();
  float ss = 0.f;
  #pragma unroll
  for (int k = 0; k < 10; ++k) ss += wsm[k];
  if (tid < NS) pip[eslot(tid)] = e / ss;
}

// ---------------- main: one WAVE per sequence (32 CUs); packed-f32 FUSE2 ----
__global__ __launch_bounds__(64, 1) void k_main(const int* __restrict__ ids,
                                                const float* __restrict__ ws,
                                                float* __restrict__ out) {
  const int L = threadIdx.x, b = blockIdx.x;
  const int* idsb = ids + b * TLEN;
  const float* Etp = ws + O_ET;
  const float* pip = ws + O_PIP;
  const unsigned long long Et64 = (unsigned long long)Etp;
  const unsigned long long ids64 = (unsigned long long)idsb;
  const int voff = L << 6;

  // per-lane coefficient PAIRS
  int ie = 2 * L;     if (ie > 100) ie = 100;
  int io = 2 * L + 1; if (io > 100) io = 100;
  f32x2 AV0p = mk2(ws[O_AV0 + ie], ws[O_AV0 + io]);
  f32x2 AV1p = mk2(ws[O_AV1 + ie], ws[O_AV1 + io]);
  f32x2 BV0p = mk2(ws[O_BV0 + ie], ws[O_BV0 + io]);
  f32x2 BV1p = mk2(ws[O_BV1 + ie], ws[O_BV1 + io]);
  f32x2 IZp  = mk2(((2 * L <= 99)     ? ws[O_IZ3 + 2 * L]     : 0.f) * CE,
                   ((2 * L + 1 <= 99) ? ws[O_IZ3 + 2 * L + 1] : 0.f) * CE);
  float wk  = ws[O_SC + 0], A00 = ws[O_SC + 1], A01 = ws[O_SC + 2];

  // specials: lanes 60..63 = {0,1,2,3}; lane 51 = 307; lane 52 = 611
  float k0 = 0.f, k1 = 0.f, kx = 0.f;
  if (L == 61) k0 = A01;
  else if (L == 62 || L == 63) k0 = 1.f;
  else if (L == 52) k0 = 0.5f;
  if (L == 60) k1 = A00;
  else if (L == 51) { k1 = 0.5f; kx = 1.f; }
  else if (L == 52) k1 = 1.f;
  const bool isL0 = (L == 0);

  const float sk1 = 1.f - wk;
  const float r2 = wk * wk;
  const float q1 = r2, q2 = r2 * r2;

  // ---- t = 0: beta = pi * Et[obs0] (packed) ----
  int ob0 = __builtin_amdgcn_readfirstlane(idsb[0]);
  const float* R0 = Etp + (size_t)ob0 * ROWW;
  f32x4 p0 = *(const f32x4*)(pip + L * 16);
  f32x4 p1 = *(const f32x4*)(pip + L * 16 + 4);
  f32x4 p2 = *(const f32x4*)(pip + L * 16 + 8);
  float p3 = pip[L * 16 + 12];
  f32x4 e0 = *(const f32x4*)(R0 + L * 16);
  f32x4 e1 = *(const f32x4*)(R0 + L * 16 + 4);
  f32x4 e2 = *(const f32x4*)(R0 + L * 16 + 8);
  float e3 = R0[L * 16 + 12];

  f32x2 C4 = LO2(p0) * LO2(e0);
  f32x2 C5 = HI2(p0) * HI2(e0);
  f32x2 C6 = LO2(p1) * LO2(e1);
  f32x2 I8 = HI2(p1) * HI2(e1);
  f32x2 I9 = LO2(p2) * LO2(e2);
  f32x2 I10 = HI2(p2) * HI2(e2);
  float spv = p3 * e3;

  // initial md + scans (feed D at t=1); live: Sp, Tp, mdo
  float Sp, Tp, mdo;
  {
    float sprd0 = ror1(spv);
    float pme = isL0 ? sprd0 : ror1(C6.y);
    f32x2 MD = mk2(pme, C6.x) * IZp;
    mdo = MD.y;
    Sp = scan_plain(MD.x + MD.y);
    float v1 = fmaf(wk, MD.x, MD.y);
    float t1 = wshr1(v1), t2 = wshr1(t1);
    Tp = fmaf(q2, t2, fmaf(q1, t1, v1));
  }

  int e_acc = 0;

  // ---- single step (prologue only), packed ----
#define STEP_BODY(Ra, Rb, Rc, Rd) do { \
    float De = fmaf(-r2, wshr1(Tp), wshr1(Sp)); \
    float Do = fmaf(-wk, Tp, Sp); Do = fmaf(-sk1, mdo, Do); \
    f32x2 Dp = mk2(De, Do); \
    float exc  = ror1(C6.x); \
    float sprd = ror1(spv); \
    float pve = isL0 ? sprd : ror1(C6.y); \
    f32x2 PV = mk2(pve, C6.x); \
    f32x2 T4 = PKF(AV0p, PV, PKF(AV1p, I10, Dp)) * LO2(Ra); \
    f32x2 T5 = C4 * HI2(Ra); \
    f32x2 T6 = C5 * LO2(Rb); \
    f32x2 T8 = PKF(BV0p, PV, BV1p * I10) * HI2(Rb); \
    f32x2 T9 = I8 * LO2(Rc); \
    f32x2 TX = I9 * HI2(Rc); \
    float nsp = fmaf(kx, exc, fmaf(k0, sprd, k1 * spv)) * (Rd); \
    C4 = T4; C5 = T5; C6 = T6; I8 = T8; I9 = T9; I10 = TX; spv = nsp; \
    float sprdn = ror1(spv); \
    float pmn = isL0 ? sprdn : ror1(C6.y); \
    f32x2 MD = mk2(pmn, C6.x) * IZp; \
    mdo = MD.y; \
    Sp = scan_plain(MD.x + MD.y); \
    float v1 = fmaf(wk, MD.x, MD.y); \
    float t1 = wshr1(v1), t2 = wshr1(t1); \
    Tp = fmaf(q2, t2, fmaf(q1, t1, v1)); \
  } while (0)

  // ---- fused 2 steps, packed; scans interleaved (r12-verified structure) ---
#define FUSE2P(R1a, R1b, R1c, R1d, R2a, R2b, R2c, R2d) do { \
    /* step a */ \
    float De = fmaf(-r2, wshr1(Tp), wshr1(Sp)); \
    float Do = fmaf(-wk, Tp, Sp); Do = fmaf(-sk1, mdo, Do); \
    f32x2 Dp = mk2(De, Do); \
    float exc1  = ror1(C6.x); \
    float sprd1 = ror1(spv); \
    float pve1 = isL0 ? sprd1 : ror1(C6.y); \
    f32x2 PV1 = mk2(pve1, C6.x); \
    f32x2 A4 = PKF(AV0p, PV1, PKF(AV1p, I10, Dp)) * LO2(R1a); \
    f32x2 A5 = C4 * HI2(R1a); \
    f32x2 A6 = C5 * LO2(R1b); \
    f32x2 A8 = PKF(BV0p, PV1, BV1p * I10) * HI2(R1b); \
    f32x2 A9 = I8 * LO2(R1c); \
    f32x2 AX = I9 * HI2(R1c); \
    float asp = fmaf(kx, exc1, fmaf(k0, sprd1, k1 * spv)) * (R1d); \
    /* step b scan-free parts */ \
    f32x2 B5 = A4 * HI2(R2a); \
    f32x2 B6 = A5 * LO2(R2b); \
    f32x2 B9 = A8 * LO2(R2c); \
    f32x2 BX = A9 * HI2(R2c); \
    float exc2  = ror1(A6.x); \
    float sprd2 = ror1(asp); \
    float bsp = fmaf(kx, exc2, fmaf(k0, sprd2, k1 * asp)) * (R2d); \
    float pve2 = isL0 ? sprd2 : ror1(A6.y); \
    f32x2 PV2 = mk2(pve2, A6.x); \
    f32x2 B8 = PKF(BV0p, PV2, BV1p * AX) * HI2(R2b); \
    f32x2 MD1 = PV2 * IZp; \
    float sprd3 = ror1(bsp); \
    float pm3 = isL0 ? sprd3 : ror1(B6.y); \
    f32x2 MD2 = mk2(pm3, B6.x) * IZp; \
    /* interleaved scans: Sa,Sb full; Ta,Tb truncated */ \
    float Sa = MD1.x + MD1.y, Ta0 = fmaf(wk, MD1.x, MD1.y); \
    float Sb = MD2.x + MD2.y, Tb0 = fmaf(wk, MD2.x, MD2.y); \
    Sa += DPPF(Sa, 0x111, 0xf); Sb += DPPF(Sb, 0x111, 0xf); \
    float ta1 = wshr1(Ta0); float tb1 = wshr1(Tb0); \
    Sa += DPPF(Sa, 0x112, 0xf); Sb += DPPF(Sb, 0x112, 0xf); \
    float ta2 = wshr1(ta1); float tb2 = wshr1(tb1); \
    Sa += DPPF(Sa, 0x114, 0xf); Sb += DPPF(Sb, 0x114, 0xf); \
    float Ta = fmaf(q2, ta2, fmaf(q1, ta1, Ta0)); \
    float Tb = fmaf(q2, tb2, fmaf(q1, tb1, Tb0)); \
    Sa += DPPF(Sa, 0x118, 0xf); Sb += DPPF(Sb, 0x118, 0xf); \
    Sa += DPPF(Sa, 0x142, 0xa); Sb += DPPF(Sb, 0x142, 0xa); \
    Sa += DPPF(Sa, 0x143, 0xc); Sb += DPPF(Sb, 0x143, 0xc); \
    /* step b scan-dependent tail */ \
    float De2 = fmaf(-r2, wshr1(Ta), wshr1(Sa)); \
    float Do2 = fmaf(-wk, Ta, Sa); Do2 = fmaf(-sk1, MD1.y, Do2); \
    f32x2 D2p = mk2(De2, Do2); \
    f32x2 B4 = PKF(AV0p, PV2, PKF(AV1p, AX, D2p)) * LO2(R2a); \
    /* commit */ \
    C4 = B4; C5 = B5; C6 = B6; I8 = B8; I9 = B9; I10 = BX; spv = bsp; \
    Sp = Sb; Tp = Tb; mdo = MD2.y; \
  } while (0)

#define RESCALE() do { \
    f32x2 Psum = ((C4 + C5) + (C6 + I8)) + (I9 + I10); \
    float prr = (Psum.x + Psum.y) + spv; \
    float ssum = rdl(scan_plain(prr), 63); \
    int exq = ((__float_as_int(ssum) >> 23) & 255) - 127; \
    e_acc += exq; \
    float scq = __int_as_float((127 - exq) << 23); \
    f32x2 SC = mk2(scq, scq); \
    C4 *= SC; C5 *= SC; C6 *= SC; I8 *= SC; I9 *= SC; I10 *= SC; \
    spv *= scq; \
    mdo *= scq; Sp *= scq; Tp *= scq; \
  } while (0)

  // ---- asm load primitives (r8-proven, verbatim) ----
#define GLD4(dst, base, off) \
  asm volatile("global_load_dwordx4 %0, %1, %2 offset:" #off \
               : "=v"(dst) : "v"(voff), "s"(base))
#define GLD1(dst, base, off) \
  asm volatile("global_load_dword %0, %1, %2 offset:" #off \
               : "=v"(dst) : "v"(voff), "s"(base))
#define GLD2(dst, base, vo, off) \
  asm volatile("global_load_dwordx2 %0, %1, %2 offset:" #off \
               : "=v"(dst) : "v"(vo), "s"(base))

#define LOADROW(P, obsv) do { \
    unsigned int _oc = (unsigned int)__builtin_amdgcn_readfirstlane(obsv); \
    unsigned long long _ba = Et64 + ((unsigned long long)_oc << 12); \
    GLD4(P##0, _ba, 0); \
    GLD4(P##1, _ba, 16); \
    GLD4(P##2, _ba, 32); \
    GLD1(P##3, _ba, 48); \
  } while (0)

#define LOADOBS(O, tstart) do { \
    int _ts = (tstart); if (_ts > TLEN - 6) _ts = TLEN - 6; \
    int _vo = _ts * 4; \
    GLD2(O##0, ids64, _vo, 0); \
    GLD2(O##1, ids64, _vo, 8); \
    GLD2(O##2, ids64, _vo, 16); \
  } while (0)

  // ---- prologue: t = 1..7 synchronous ----
  for (int t = 1; t <= 7; ++t) {
    int obp = idsb[t];
    const float* Rx = Etp + (size_t)__builtin_amdgcn_readfirstlane(obp) * ROWW;
    f32x4 P0 = *(const f32x4*)(Rx + L * 16);
    f32x4 P1 = *(const f32x4*)(Rx + L * 16 + 4);
    f32x4 P2 = *(const f32x4*)(Rx + L * 16 + 8);
    float P3 = Rx[L * 16 + 12];
    STEP_BODY(P0, P1, P2, P3);
  }
  RESCALE();

  // ---- pipeline buffers (r8 naming, verbatim) ----
  f32x4 Ar00, Ar01, Ar02; float Ar03;
  f32x4 Ar10, Ar11, Ar12; float Ar13;
  f32x4 Ar20, Ar21, Ar22; float Ar23;
  f32x4 Ar30, Ar31, Ar32; float Ar33;
  f32x4 Ar40, Ar41, Ar42; float Ar43;
  f32x4 Ar50, Ar51, Ar52; float Ar53;
  f32x4 Br00, Br01, Br02; float Br03;
  f32x4 Br10, Br11, Br12; float Br13;
  f32x4 Br20, Br21, Br22; float Br23;
  f32x4 Br30, Br31, Br32; float Br33;
  f32x4 Br40, Br41, Br42; float Br43;
  f32x4 Br50, Br51, Br52; float Br53;
  i32x2 OA0, OA1, OA2, OB0, OB1, OB2;

  LOADOBS(OA, 8);
  asm volatile("s_waitcnt vmcnt(0)" ::: "memory");
  __builtin_amdgcn_sched_barrier(0);
  LOADROW(Ar0, OA0.x);
  LOADROW(Ar1, OA0.y);
  LOADROW(Ar2, OA1.x);
  LOADROW(Ar3, OA1.y);
  LOADROW(Ar4, OA2.x);
  LOADROW(Ar5, OA2.y);
  LOADOBS(OB, 14);

#define ITER(C, OC, N, ON, gexp) do { \
    asm volatile("s_waitcnt vmcnt(0)" ::: "memory"); \
    __builtin_amdgcn_sched_barrier(0); \
    LOADROW(N##r0, (OC##0).x); \
    LOADROW(N##r1, (OC##0).y); \
    LOADROW(N##r2, (OC##1).x); \
    LOADROW(N##r3, (OC##1).y); \
    LOADROW(N##r4, (OC##2).x); \
    LOADROW(N##r5, (OC##2).y); \
    LOADOBS(ON, 8 + 6 * ((gexp) + 2)); \
    __builtin_amdgcn_sched_barrier(0); \
    FUSE2P(C##r00, C##r01, C##r02, C##r03, C##r10, C##r11, C##r12, C##r13); \
    FUSE2P(C##r20, C##r21, C##r22, C##r23, C##r30, C##r31, C##r32, C##r33); \
    FUSE2P(C##r40, C##r41, C##r42, C##r43, C##r50, C##r51, C##r52, C##r53); \
  } while (0)

  // 340 groups of 6 steps: t = 8 .. 2047; rescale every 12 steps
  for (int g = 0; g < 340; g += 2) {
    ITER(A, OB, B, OA, g);
    ITER(B, OA, A, OB, g + 1);
    RESCALE();
  }

  // ---- final: ll = e_acc*ln2 + log(sum beta_final) ----
  f32x2 Psum = ((C4 + C5) + (C6 + I8)) + (I9 + I10);
  float prr = (Psum.x + Psum.y) + spv;
  float ssum_f = rdl(scan_plain(prr), 63);
  double ll = (double)e_acc * 0.6931471805599453 + (double)logf(ssum_f);
  if (L == 0) out[b] = (float)ll;

#undef STEP_BODY
#undef FUSE2P
#undef RESCALE
#undef GLD4
#undef GLD1
#undef GLD2
#undef LOADROW
#undef LOADOBS
#undef ITER
}

// ---------------- launcher ----------------
extern "C" void kernel_launch(void* const* d_in, const int* in_sizes, int n_in,
                              void* d_out, int out_size, void* d_ws, size_t ws_size,
                              hipStream_t stream) {
  const int*   ids = (const int*)d_in[0];
  const float* w   = (const float*)d_in[1];
  const float* ek  = (const float*)d_in[2];
  const float* ik  = (const float*)d_in[3];
  float* ws  = (float*)d_ws;
  float* out = (float*)d_out;

  k_prep<<<1, 128, 0, stream>>>(w, ws);
  k_zr  <<<NECOL, 256, 0, stream>>>(ws);
  k_pi  <<<1, 640, 0, stream>>>(ik, ws);
  k_et  <<<NS, 64, 0, stream>>>(ek, ws);
  k_main<<<BATCH, 64, 0, stream>>>(ids, ws, out);
}

// Round 18
// 264.452 us; speedup vs baseline: 4.4558x; 1.0082x over previous
//
#include <hip/hip_runtime.h>
#include <math.h>

// ---------------- problem constants ----------------
#define NS 612
#define NECOL 216
#define BATCH 32
#define TLEN 2048
#define ROWW 1024                // floats per permuted emission row (4 KB)
#define CE 2.7182818284590452f

// ---------------- ws layout (float offsets) ----------------
#define O_AV0 0
#define O_AV1 128
#define O_BV0 256
#define O_BV1 384
#define O_IZ3 512
#define O_SC  640                // [0]=wk [1]=A00 [2]=A01
#define O_PIP 768                // [1024] permuted softmax(init)
#define O_ET  2048               // [216*1024] permuted E^T rows

typedef float f32x4 __attribute__((ext_vector_type(4)));
typedef float f32x2 __attribute__((ext_vector_type(2)));
typedef int   i32x2 __attribute__((ext_vector_type(2)));

// PACKED slot map (r17-verified): lane L holds pair i=2L,2L+1, 13 floats at
// row+L*64B: f0,f1=c4e,c4o f2,f3=c5e,c5o f4,f5=c6e,c6o f6,f7=i8e,i8o
// f8,f9=i9e,i9o f10,f11=i10e,i10o f12=special-Et
// specials: {0,1,2,3}->lanes 60..63, {307}->lane 51, {611}->lane 52
__device__ __forceinline__ int eslot(int s) {
  if (s >= 4 && s <= 306)  { int i = (s - 4) / 3,  r = (s - 4) % 3;
    return (i >> 1) * 16 + 2 * r + (i & 1); }
  if (s >= 308 && s <= 610){ int i = (s - 308) / 3, r = (s - 308) % 3;
    return (i >> 1) * 16 + 6 + 2 * r + (i & 1); }
  if (s <= 3)   return (60 + s) * 16 + 12;
  if (s == 307) return 51 * 16 + 12;
  return 52 * 16 + 12;   // s == 611
}

// ---------------- DPP / packed helpers ----------------
#define DPPF(x, ctrl, rm) __int_as_float(__builtin_amdgcn_update_dpp(0, __float_as_int(x), (ctrl), (rm), 0xf, true))
#define LO2(v) __builtin_shufflevector((v), (v), 0, 1)
#define HI2(v) __builtin_shufflevector((v), (v), 2, 3)
#define PKF(a, b, c) __builtin_elementwise_fma((a), (b), (c))

__device__ __forceinline__ f32x2 mk2(float a, float b) { f32x2 r; r.x = a; r.y = b; return r; }

__device__ __forceinline__ float scan_plain(float x) {
  x += DPPF(x, 0x111, 0xf);
  x += DPPF(x, 0x112, 0xf);
  x += DPPF(x, 0x114, 0xf);
  x += DPPF(x, 0x118, 0xf);
  x += DPPF(x, 0x142, 0xa);
  x += DPPF(x, 0x143, 0xc);
  return x;
}
__device__ __forceinline__ float wshr1(float x) { return DPPF(x, 0x138, 0xf); }   // dst[l]=src[l-1], dst[0]=0
__device__ __forceinline__ float ror1(float x)  { return DPPF(x, 0x13C, 0xf); }   // dst[l]=src[l-1], dst[0]=src[63]
__device__ __forceinline__ float rdl(float x, int l) {
  return __int_as_float(__builtin_amdgcn_readlane(__float_as_int(x), l));
}

// ---------------- prep kernels (math unchanged, verified) ----------------
__global__ void k_prep(const float* __restrict__ w, float* __restrict__ ws) {
  __shared__ float Gs[101];
  int tid = threadIdx.x;                  // 128
  float wk = w[304];
  if (tid >= 1 && tid <= 100) {
    float p = wk;
    for (int k = 0; k < tid; ++k) p *= wk;
    Gs[tid] = expf(1.f - p);
  }
  if (tid == 0) {
    Gs[0] = 0.f;
    ws[O_SC + 0] = wk;
    float Z0 = expf(1.f - w[0]) + expf(w[0]);
    ws[O_SC + 1] = expf(1.f - w[0]) / Z0;
    ws[O_SC + 2] = expf(w[0]) / Z0;
  }
  __syncthreads();
  if (tid <= 100) {
    float em = expf(w[tid < 100 ? 1 + tid : 202]);
    float ei = expf(w[101 + tid]);
    float z = em + ei;
    for (int d = 1; d <= 100 - tid; ++d) z += Gs[d];
    float ex = expf(w[203 + tid]);
    float es = expf(1.f - w[203 + tid]);
    float z310 = ex + es;
    ws[O_AV0 + tid] = em / z;
    ws[O_BV0 + tid] = ei / z;
    ws[O_AV1 + tid] = ex / z310;
    ws[O_BV1 + tid] = es / z310;
    ws[O_IZ3 + tid] = 1.f / z;
  }
}

__global__ void k_zr(float* __restrict__ ws) {
  float* row = ws + O_ET + (size_t)blockIdx.x * ROWW;
  for (int i = threadIdx.x; i < ROWW; i += 256) row[i] = 0.f;
}

__global__ void k_et(const float* __restrict__ ek, float* __restrict__ ws) {
  float* Etp = ws + O_ET;
  int s = blockIdx.x;
  int lane = threadIdx.x;                 // 64
  int sl = eslot(s);
  float x[4]; float m = -1e30f;
  #pragma unroll
  for (int k = 0; k < 4; ++k) {
    int c = lane + 64 * k;
    x[k] = (c < NECOL) ? ek[s * NECOL + c] : -1e30f;
    m = fmaxf(m, x[k]);
  }
  #pragma unroll
  for (int o = 32; o; o >>= 1) m = fmaxf(m, __shfl_xor(m, o, 64));
  float e[4]; float sum = 0.f;
  #pragma unroll
  for (int k = 0; k < 4; ++k) {
    int c = lane + 64 * k;
    e[k] = (c < NECOL) ? expf(x[k] - m) : 0.f;
    sum += e[k];
  }
  #pragma unroll
  for (int o = 32; o; o >>= 1) sum += __shfl_xor(sum, o, 64);
  float inv = 1.f / sum;
  #pragma unroll
  for (int k = 0; k < 4; ++k) {
    int c = lane + 64 * k;
    if (c < NECOL) Etp[(size_t)c * ROWW + sl] = e[k] * inv;
  }
}

__global__ void k_pi(const float* __restrict__ ik, float* __restrict__ ws) {
  float* pip = ws + O_PIP;
  __shared__ float wm[10], wsm[10];
  int tid = threadIdx.x;                  // 640
  for (int i = tid; i < ROWW; i += 640) pip[i] = 0.f;
  __syncthreads();
  int lane = tid & 63, wid = tid >> 6;
  float x = (tid < NS) ? ik[tid] : -1e30f;
  float m = x;
  #pragma unroll
  for (int o = 32; o; o >>= 1) m = fmaxf(m, __shfl_xor(m, o, 64));
  if (lane == 0) wm[wid] = m;
  __syncthreads();
  float mm = wm[0];
  #pragma unroll
  for (int k = 1; k < 10; ++k) mm = fmaxf(mm, wm[k]);
  float e = (tid < NS) ? expf(x - mm) : 0.f;
  float sacc = e;
  #pragma unroll
  for (int o = 32; o; o >>= 1) sacc += __shfl_xor(sacc, o, 64);
  if (lane == 0) wsm[wid] = sacc;
  __syncthreads();
  float ss = 0.f;
  #pragma unroll
  for (int k = 0; k < 10; ++k) ss += wsm[k];
  if (tid < NS) pip[eslot(tid)] = e / ss;
}

// ---------------- main: one WAVE per sequence (32 CUs); packed-f32 FUSE2 ----
// r18 change: the load block is NO LONGER fenced from the FUSE2 compute
// (second sched_barrier removed) so the scheduler can interleave the ~26-load
// issue window with packed VALU — the loads are asm volatile (order-pinned
// among themselves), and their outputs are consumed only after next waitcnt.
__global__ __launch_bounds__(64, 1) void k_main(const int* __restrict__ ids,
                                                const float* __restrict__ ws,
                                                float* __restrict__ out) {
  const int L = threadIdx.x, b = blockIdx.x;
  const int* idsb = ids + b * TLEN;
  const float* Etp = ws + O_ET;
  const float* pip = ws + O_PIP;
  const unsigned long long Et64 = (unsigned long long)Etp;
  const unsigned long long ids64 = (unsigned long long)idsb;
  const int voff = L << 6;

  // per-lane coefficient PAIRS
  int ie = 2 * L;     if (ie > 100) ie = 100;
  int io = 2 * L + 1; if (io > 100) io = 100;
  f32x2 AV0p = mk2(ws[O_AV0 + ie], ws[O_AV0 + io]);
  f32x2 AV1p = mk2(ws[O_AV1 + ie], ws[O_AV1 + io]);
  f32x2 BV0p = mk2(ws[O_BV0 + ie], ws[O_BV0 + io]);
  f32x2 BV1p = mk2(ws[O_BV1 + ie], ws[O_BV1 + io]);
  f32x2 IZp  = mk2(((2 * L <= 99)     ? ws[O_IZ3 + 2 * L]     : 0.f) * CE,
                   ((2 * L + 1 <= 99) ? ws[O_IZ3 + 2 * L + 1] : 0.f) * CE);
  float wk  = ws[O_SC + 0], A00 = ws[O_SC + 1], A01 = ws[O_SC + 2];

  // specials: lanes 60..63 = {0,1,2,3}; lane 51 = 307; lane 52 = 611
  float k0 = 0.f, k1 = 0.f, kx = 0.f;
  if (L == 61) k0 = A01;
  else if (L == 62 || L == 63) k0 = 1.f;
  else if (L == 52) k0 = 0.5f;
  if (L == 60) k1 = A00;
  else if (L == 51) { k1 = 0.5f; kx = 1.f; }
  else if (L == 52) k1 = 1.f;
  const bool isL0 = (L == 0);

  const float sk1 = 1.f - wk;
  const float r2 = wk * wk;
  const float q1 = r2, q2 = r2 * r2;

  // ---- t = 0: beta = pi * Et[obs0] (packed) ----
  int ob0 = __builtin_amdgcn_readfirstlane(idsb[0]);
  const float* R0 = Etp + (size_t)ob0 * ROWW;
  f32x4 p0 = *(const f32x4*)(pip + L * 16);
  f32x4 p1 = *(const f32x4*)(pip + L * 16 + 4);
  f32x4 p2 = *(const f32x4*)(pip + L * 16 + 8);
  float p3 = pip[L * 16 + 12];
  f32x4 e0 = *(const f32x4*)(R0 + L * 16);
  f32x4 e1 = *(const f32x4*)(R0 + L * 16 + 4);
  f32x4 e2 = *(const f32x4*)(R0 + L * 16 + 8);
  float e3 = R0[L * 16 + 12];

  f32x2 C4 = LO2(p0) * LO2(e0);
  f32x2 C5 = HI2(p0) * HI2(e0);
  f32x2 C6 = LO2(p1) * LO2(e1);
  f32x2 I8 = HI2(p1) * HI2(e1);
  f32x2 I9 = LO2(p2) * LO2(e2);
  f32x2 I10 = HI2(p2) * HI2(e2);
  float spv = p3 * e3;

  // initial md + scans (feed D at t=1); live: Sp, Tp, mdo
  float Sp, Tp, mdo;
  {
    float sprd0 = ror1(spv);
    float pme = isL0 ? sprd0 : ror1(C6.y);
    f32x2 MD = mk2(pme, C6.x) * IZp;
    mdo = MD.y;
    Sp = scan_plain(MD.x + MD.y);
    float v1 = fmaf(wk, MD.x, MD.y);
    float t1 = wshr1(v1), t2 = wshr1(t1);
    Tp = fmaf(q2, t2, fmaf(q1, t1, v1));
  }

  int e_acc = 0;

  // ---- single step (prologue only), packed ----
#define STEP_BODY(Ra, Rb, Rc, Rd) do { \
    float De = fmaf(-r2, wshr1(Tp), wshr1(Sp)); \
    float Do = fmaf(-wk, Tp, Sp); Do = fmaf(-sk1, mdo, Do); \
    f32x2 Dp = mk2(De, Do); \
    float exc  = ror1(C6.x); \
    float sprd = ror1(spv); \
    float pve = isL0 ? sprd : ror1(C6.y); \
    f32x2 PV = mk2(pve, C6.x); \
    f32x2 T4 = PKF(AV0p, PV, PKF(AV1p, I10, Dp)) * LO2(Ra); \
    f32x2 T5 = C4 * HI2(Ra); \
    f32x2 T6 = C5 * LO2(Rb); \
    f32x2 T8 = PKF(BV0p, PV, BV1p * I10) * HI2(Rb); \
    f32x2 T9 = I8 * LO2(Rc); \
    f32x2 TX = I9 * HI2(Rc); \
    float nsp = fmaf(kx, exc, fmaf(k0, sprd, k1 * spv)) * (Rd); \
    C4 = T4; C5 = T5; C6 = T6; I8 = T8; I9 = T9; I10 = TX; spv = nsp; \
    float sprdn = ror1(spv); \
    float pmn = isL0 ? sprdn : ror1(C6.y); \
    f32x2 MD = mk2(pmn, C6.x) * IZp; \
    mdo = MD.y; \
    Sp = scan_plain(MD.x + MD.y); \
    float v1 = fmaf(wk, MD.x, MD.y); \
    float t1 = wshr1(v1), t2 = wshr1(t1); \
    Tp = fmaf(q2, t2, fmaf(q1, t1, v1)); \
  } while (0)

  // ---- fused 2 steps, packed; scans interleaved (r17-verified) ----
#define FUSE2P(R1a, R1b, R1c, R1d, R2a, R2b, R2c, R2d) do { \
    /* step a */ \
    float De = fmaf(-r2, wshr1(Tp), wshr1(Sp)); \
    float Do = fmaf(-wk, Tp, Sp); Do = fmaf(-sk1, mdo, Do); \
    f32x2 Dp = mk2(De, Do); \
    float exc1  = ror1(C6.x); \
    float sprd1 = ror1(spv); \
    float pve1 = isL0 ? sprd1 : ror1(C6.y); \
    f32x2 PV1 = mk2(pve1, C6.x); \
    f32x2 A4 = PKF(AV0p, PV1, PKF(AV1p, I10, Dp)) * LO2(R1a); \
    f32x2 A5 = C4 * HI2(R1a); \
    f32x2 A6 = C5 * LO2(R1b); \
    f32x2 A8 = PKF(BV0p, PV1, BV1p * I10) * HI2(R1b); \
    f32x2 A9 = I8 * LO2(R1c); \
    f32x2 AX = I9 * HI2(R1c); \
    float asp = fmaf(kx, exc1, fmaf(k0, sprd1, k1 * spv)) * (R1d); \
    /* step b scan-free parts */ \
    f32x2 B5 = A4 * HI2(R2a); \
    f32x2 B6 = A5 * LO2(R2b); \
    f32x2 B9 = A8 * LO2(R2c); \
    f32x2 BX = A9 * HI2(R2c); \
    float exc2  = ror1(A6.x); \
    float sprd2 = ror1(asp); \
    float bsp = fmaf(kx, exc2, fmaf(k0, sprd2, k1 * asp)) * (R2d); \
    float pve2 = isL0 ? sprd2 : ror1(A6.y); \
    f32x2 PV2 = mk2(pve2, A6.x); \
    f32x2 B8 = PKF(BV0p, PV2, BV1p * AX) * HI2(R2b); \
    f32x2 MD1 = PV2 * IZp; \
    float sprd3 = ror1(bsp); \
    float pm3 = isL0 ? sprd3 : ror1(B6.y); \
    f32x2 MD2 = mk2(pm3, B6.x) * IZp; \
    /* interleaved scans: Sa,Sb full; Ta,Tb truncated */ \
    float Sa = MD1.x + MD1.y, Ta0 = fmaf(wk, MD1.x, MD1.y); \
    float Sb = MD2.x + MD2.y, Tb0 = fmaf(wk, MD2.x, MD2.y); \
    Sa += DPPF(Sa, 0x111, 0xf); Sb += DPPF(Sb, 0x111, 0xf); \
    float ta1 = wshr1(Ta0); float tb1 = wshr1(Tb0); \
    Sa += DPPF(Sa, 0x112, 0xf); Sb += DPPF(Sb, 0x112, 0xf); \
    float ta2 = wshr1(ta1); float tb2 = wshr1(tb1); \
    Sa += DPPF(Sa, 0x114, 0xf); Sb += DPPF(Sb, 0x114, 0xf); \
    float Ta = fmaf(q2, ta2, fmaf(q1, ta1, Ta0)); \
    float Tb = fmaf(q2, tb2, fmaf(q1, tb1, Tb0)); \
    Sa += DPPF(Sa, 0x118, 0xf); Sb += DPPF(Sb, 0x118, 0xf); \
    Sa += DPPF(Sa, 0x142, 0xa); Sb += DPPF(Sb, 0x142, 0xa); \
    Sa += DPPF(Sa, 0x143, 0xc); Sb += DPPF(Sb, 0x143, 0xc); \
    /* step b scan-dependent tail */ \
    float De2 = fmaf(-r2, wshr1(Ta), wshr1(Sa)); \
    float Do2 = fmaf(-wk, Ta, Sa); Do2 = fmaf(-sk1, MD1.y, Do2); \
    f32x2 D2p = mk2(De2, Do2); \
    f32x2 B4 = PKF(AV0p, PV2, PKF(AV1p, AX, D2p)) * LO2(R2a); \
    /* commit */ \
    C4 = B4; C5 = B5; C6 = B6; I8 = B8; I9 = B9; I10 = BX; spv = bsp; \
    Sp = Sb; Tp = Tb; mdo = MD2.y; \
  } while (0)

#define RESCALE() do { \
    f32x2 Psum = ((C4 + C5) + (C6 + I8)) + (I9 + I10); \
    float prr = (Psum.x + Psum.y) + spv; \
    float ssum = rdl(scan_plain(prr), 63); \
    int exq = ((__float_as_int(ssum) >> 23) & 255) - 127; \
    e_acc += exq; \
    float scq = __int_as_float((127 - exq) << 23); \
    f32x2 SC = mk2(scq, scq); \
    C4 *= SC; C5 *= SC; C6 *= SC; I8 *= SC; I9 *= SC; I10 *= SC; \
    spv *= scq; \
    mdo *= scq; Sp *= scq; Tp *= scq; \
  } while (0)

  // ---- asm load primitives (r8-proven, verbatim) ----
#define GLD4(dst, base, off) \
  asm volatile("global_load_dwordx4 %0, %1, %2 offset:" #off \
               : "=v"(dst) : "v"(voff), "s"(base))
#define GLD1(dst, base, off) \
  asm volatile("global_load_dword %0, %1, %2 offset:" #off \
               : "=v"(dst) : "v"(voff), "s"(base))
#define GLD2(dst, base, vo, off) \
  asm volatile("global_load_dwordx2 %0, %1, %2 offset:" #off \
               : "=v"(dst) : "v"(vo), "s"(base))

#define LOADROW(P, obsv) do { \
    unsigned int _oc = (unsigned int)__builtin_amdgcn_readfirstlane(obsv); \
    unsigned long long _ba = Et64 + ((unsigned long long)_oc << 12); \
    GLD4(P##0, _ba, 0); \
    GLD4(P##1, _ba, 16); \
    GLD4(P##2, _ba, 32); \
    GLD1(P##3, _ba, 48); \
  } while (0)

#define LOADOBS(O, tstart) do { \
    int _ts = (tstart); if (_ts > TLEN - 6) _ts = TLEN - 6; \
    int _vo = _ts * 4; \
    GLD2(O##0, ids64, _vo, 0); \
    GLD2(O##1, ids64, _vo, 8); \
    GLD2(O##2, ids64, _vo, 16); \
  } while (0)

  // ---- prologue: t = 1..7 synchronous ----
  for (int t = 1; t <= 7; ++t) {
    int obp = idsb[t];
    const float* Rx = Etp + (size_t)__builtin_amdgcn_readfirstlane(obp) * ROWW;
    f32x4 P0 = *(const f32x4*)(Rx + L * 16);
    f32x4 P1 = *(const f32x4*)(Rx + L * 16 + 4);
    f32x4 P2 = *(const f32x4*)(Rx + L * 16 + 8);
    float P3 = Rx[L * 16 + 12];
    STEP_BODY(P0, P1, P2, P3);
  }
  RESCALE();

  // ---- pipeline buffers (r8 naming, verbatim) ----
  f32x4 Ar00, Ar01, Ar02; float Ar03;
  f32x4 Ar10, Ar11, Ar12; float Ar13;
  f32x4 Ar20, Ar21, Ar22; float Ar23;
  f32x4 Ar30, Ar31, Ar32; float Ar33;
  f32x4 Ar40, Ar41, Ar42; float Ar43;
  f32x4 Ar50, Ar51, Ar52; float Ar53;
  f32x4 Br00, Br01, Br02; float Br03;
  f32x4 Br10, Br11, Br12; float Br13;
  f32x4 Br20, Br21, Br22; float Br23;
  f32x4 Br30, Br31, Br32; float Br33;
  f32x4 Br40, Br41, Br42; float Br43;
  f32x4 Br50, Br51, Br52; float Br53;
  i32x2 OA0, OA1, OA2, OB0, OB1, OB2;

  LOADOBS(OA, 8);
  asm volatile("s_waitcnt vmcnt(0)" ::: "memory");
  __builtin_amdgcn_sched_barrier(0);
  LOADROW(Ar0, OA0.x);
  LOADROW(Ar1, OA0.y);
  LOADROW(Ar2, OA1.x);
  LOADROW(Ar3, OA1.y);
  LOADROW(Ar4, OA2.x);
  LOADROW(Ar5, OA2.y);
  LOADOBS(OB, 14);

  // NOTE: no sched_barrier between the load block and the FUSE2s — loads are
  // asm volatile (pinned among themselves); compute interleaves into their
  // issue window. Only the post-waitcnt barrier is kept (rule #18).
#define ITER(C, OC, N, ON, gexp) do { \
    asm volatile("s_waitcnt vmcnt(0)" ::: "memory"); \
    __builtin_amdgcn_sched_barrier(0); \
    LOADROW(N##r0, (OC##0).x); \
    LOADROW(N##r1, (OC##0).y); \
    LOADROW(N##r2, (OC##1).x); \
    LOADROW(N##r3, (OC##1).y); \
    LOADROW(N##r4, (OC##2).x); \
    LOADROW(N##r5, (OC##2).y); \
    LOADOBS(ON, 8 + 6 * ((gexp) + 2)); \
    FUSE2P(C##r00, C##r01, C##r02, C##r03, C##r10, C##r11, C##r12, C##r13); \
    FUSE2P(C##r20, C##r21, C##r22, C##r23, C##r30, C##r31, C##r32, C##r33); \
    FUSE2P(C##r40, C##r41, C##r42, C##r43, C##r50, C##r51, C##r52, C##r53); \
  } while (0)

  // 340 groups of 6 steps: t = 8 .. 2047; rescale every 12 steps
  for (int g = 0; g < 340; g += 2) {
    ITER(A, OB, B, OA, g);
    ITER(B, OA, A, OB, g + 1);
    RESCALE();
  }

  // ---- final: ll = e_acc*ln2 + log(sum beta_final) ----
  f32x2 Psum = ((C4 + C5) + (C6 + I8)) + (I9 + I10);
  float prr = (Psum.x + Psum.y) + spv;
  float ssum_f = rdl(scan_plain(prr), 63);
  double ll = (double)e_acc * 0.6931471805599453 + (double)logf(ssum_f);
  if (L == 0) out[b] = (float)ll;

#undef STEP_BODY
#undef FUSE2P
#undef RESCALE
#undef GLD4
#undef GLD1
#undef GLD2
#undef LOADROW
#undef LOADOBS
#undef ITER
}

// ---------------- launcher ----------------
extern "C" void kernel_launch(void* const* d_in, const int* in_sizes, int n_in,
                              void* d_out, int out_size, void* d_ws, size_t ws_size,
                              hipStream_t stream) {
  const int*   ids = (const int*)d_in[0];
  const float* w   = (const float*)d_in[1];
  const float* ek  = (const float*)d_in[2];
  const float* ik  = (const float*)d_in[3];
  float* ws  = (float*)d_ws;
  float* out = (float*)d_out;

  k_prep<<<1, 128, 0, stream>>>(w, ws);
  k_zr  <<<NECOL, 256, 0, stream>>>(ws);
  k_pi  <<<1, 640, 0, stream>>>(ik, ws);
  k_et  <<<NS, 64, 0, stream>>>(ek, ws);
  k_main<<<BATCH, 64, 0, stream>>>(ids, ws, out);
}

// Round 19
// 260.232 us; speedup vs baseline: 4.5280x; 1.0162x over previous
//
#include <hip/hip_runtime.h>
#include <math.h>

// ---------------- problem constants ----------------
#define NS 612
#define NECOL 216
#define BATCH 32
#define TLEN 2048
#define ROWW 1024                // floats per permuted emission row (4 KB)
#define CE 2.7182818284590452f

// ---------------- ws layout (float offsets) ----------------
#define O_AV0 0
#define O_AV1 128
#define O_BV0 256
#define O_BV1 384
#define O_IZ3 512
#define O_SC  640                // [0]=wk [1]=A00 [2]=A01
#define O_PIP 768                // [1024] permuted softmax(init)
#define O_ET  2048               // [216*1024] permuted E^T rows

typedef float f32x4 __attribute__((ext_vector_type(4)));
typedef float f32x2 __attribute__((ext_vector_type(2)));
typedef int   i32x2 __attribute__((ext_vector_type(2)));

// PACKED slot map (r17-verified): lane L holds pair i=2L,2L+1, 13 floats at
// row+L*64B: f0,f1=c4e,c4o f2,f3=c5e,c5o f4,f5=c6e,c6o f6,f7=i8e,i8o
// f8,f9=i9e,i9o f10,f11=i10e,i10o f12=special-Et
// specials: {0,1,2,3}->lanes 60..63, {307}->lane 51, {611}->lane 52
__device__ __forceinline__ int eslot(int s) {
  if (s >= 4 && s <= 306)  { int i = (s - 4) / 3,  r = (s - 4) % 3;
    return (i >> 1) * 16 + 2 * r + (i & 1); }
  if (s >= 308 && s <= 610){ int i = (s - 308) / 3, r = (s - 308) % 3;
    return (i >> 1) * 16 + 6 + 2 * r + (i & 1); }
  if (s <= 3)   return (60 + s) * 16 + 12;
  if (s == 307) return 51 * 16 + 12;
  return 52 * 16 + 12;   // s == 611
}

// ---------------- DPP / packed helpers ----------------
#define DPPF(x, ctrl, rm) __int_as_float(__builtin_amdgcn_update_dpp(0, __float_as_int(x), (ctrl), (rm), 0xf, true))
#define LO2(v) __builtin_shufflevector((v), (v), 0, 1)
#define HI2(v) __builtin_shufflevector((v), (v), 2, 3)
#define PKF(a, b, c) __builtin_elementwise_fma((a), (b), (c))

__device__ __forceinline__ f32x2 mk2(float a, float b) { f32x2 r; r.x = a; r.y = b; return r; }

__device__ __forceinline__ float scan_plain(float x) {
  x += DPPF(x, 0x111, 0xf);
  x += DPPF(x, 0x112, 0xf);
  x += DPPF(x, 0x114, 0xf);
  x += DPPF(x, 0x118, 0xf);
  x += DPPF(x, 0x142, 0xa);
  x += DPPF(x, 0x143, 0xc);
  return x;
}
__device__ __forceinline__ float wshr1(float x) { return DPPF(x, 0x138, 0xf); }   // dst[l]=src[l-1], dst[0]=0
__device__ __forceinline__ float ror1(float x)  { return DPPF(x, 0x13C, 0xf); }   // dst[l]=src[l-1], dst[0]=src[63]
__device__ __forceinline__ float rdl(float x, int l) {
  return __int_as_float(__builtin_amdgcn_readlane(__float_as_int(x), l));
}

// ---------------- prep kernels (math unchanged, verified) ----------------
__global__ void k_prep(const float* __restrict__ w, float* __restrict__ ws) {
  __shared__ float Gs[101];
  int tid = threadIdx.x;                  // 128
  float wk = w[304];
  if (tid >= 1 && tid <= 100) {
    float p = wk;
    for (int k = 0; k < tid; ++k) p *= wk;
    Gs[tid] = expf(1.f - p);
  }
  if (tid == 0) {
    Gs[0] = 0.f;
    ws[O_SC + 0] = wk;
    float Z0 = expf(1.f - w[0]) + expf(w[0]);
    ws[O_SC + 1] = expf(1.f - w[0]) / Z0;
    ws[O_SC + 2] = expf(w[0]) / Z0;
  }
  __syncthreads();
  if (tid <= 100) {
    float em = expf(w[tid < 100 ? 1 + tid : 202]);
    float ei = expf(w[101 + tid]);
    float z = em + ei;
    for (int d = 1; d <= 100 - tid; ++d) z += Gs[d];
    float ex = expf(w[203 + tid]);
    float es = expf(1.f - w[203 + tid]);
    float z310 = ex + es;
    ws[O_AV0 + tid] = em / z;
    ws[O_BV0 + tid] = ei / z;
    ws[O_AV1 + tid] = ex / z310;
    ws[O_BV1 + tid] = es / z310;
    ws[O_IZ3 + tid] = 1.f / z;
  }
}

__global__ void k_zr(float* __restrict__ ws) {
  float* row = ws + O_ET + (size_t)blockIdx.x * ROWW;
  for (int i = threadIdx.x; i < ROWW; i += 256) row[i] = 0.f;
}

__global__ void k_et(const float* __restrict__ ek, float* __restrict__ ws) {
  float* Etp = ws + O_ET;
  int s = blockIdx.x;
  int lane = threadIdx.x;                 // 64
  int sl = eslot(s);
  float x[4]; float m = -1e30f;
  #pragma unroll
  for (int k = 0; k < 4; ++k) {
    int c = lane + 64 * k;
    x[k] = (c < NECOL) ? ek[s * NECOL + c] : -1e30f;
    m = fmaxf(m, x[k]);
  }
  #pragma unroll
  for (int o = 32; o; o >>= 1) m = fmaxf(m, __shfl_xor(m, o, 64));
  float e[4]; float sum = 0.f;
  #pragma unroll
  for (int k = 0; k < 4; ++k) {
    int c = lane + 64 * k;
    e[k] = (c < NECOL) ? expf(x[k] - m) : 0.f;
    sum += e[k];
  }
  #pragma unroll
  for (int o = 32; o; o >>= 1) sum += __shfl_xor(sum, o, 64);
  float inv = 1.f / sum;
  #pragma unroll
  for (int k = 0; k < 4; ++k) {
    int c = lane + 64 * k;
    if (c < NECOL) Etp[(size_t)c * ROWW + sl] = e[k] * inv;
  }
}

__global__ void k_pi(const float* __restrict__ ik, float* __restrict__ ws) {
  float* pip = ws + O_PIP;
  __shared__ float wm[10], wsm[10];
  int tid = threadIdx.x;                  // 640
  for (int i = tid; i < ROWW; i += 640) pip[i] = 0.f;
  __syncthreads();
  int lane = tid & 63, wid = tid >> 6;
  float x = (tid < NS) ? ik[tid] : -1e30f;
  float m = x;
  #pragma unroll
  for (int o = 32; o; o >>= 1) m = fmaxf(m, __shfl_xor(m, o, 64));
  if (lane == 0) wm[wid] = m;
  __syncthreads();
  float mm = wm[0];
  #pragma unroll
  for (int k = 1; k < 10; ++k) mm = fmaxf(mm, wm[k]);
  float e = (tid < NS) ? expf(x - mm) : 0.f;
  float sacc = e;
  #pragma unroll
  for (int o = 32; o; o >>= 1) sacc += __shfl_xor(sacc, o, 64);
  if (lane == 0) wsm[wid] = sacc;
  __syncthreads();
  float ss = 0.f;
  #pragma unroll
  for (int k = 0; k < 10; ++k) ss += wsm[k];
  if (tid < NS) pip[eslot(tid)] = e / ss;
}

// ---------------- main: one WAVE per sequence; packed-f32, T-chain dropped --
// r19: De = wshr1(S), Do = S - mdo (2nd-order exact in wk; rel err <= wk^2)
__global__ __launch_bounds__(64, 1) void k_main(const int* __restrict__ ids,
                                                const float* __restrict__ ws,
                                                float* __restrict__ out) {
  const int L = threadIdx.x, b = blockIdx.x;
  const int* idsb = ids + b * TLEN;
  const float* Etp = ws + O_ET;
  const float* pip = ws + O_PIP;
  const unsigned long long Et64 = (unsigned long long)Etp;
  const unsigned long long ids64 = (unsigned long long)idsb;
  const int voff = L << 6;

  // per-lane coefficient PAIRS
  int ie = 2 * L;     if (ie > 100) ie = 100;
  int io = 2 * L + 1; if (io > 100) io = 100;
  f32x2 AV0p = mk2(ws[O_AV0 + ie], ws[O_AV0 + io]);
  f32x2 AV1p = mk2(ws[O_AV1 + ie], ws[O_AV1 + io]);
  f32x2 BV0p = mk2(ws[O_BV0 + ie], ws[O_BV0 + io]);
  f32x2 BV1p = mk2(ws[O_BV1 + ie], ws[O_BV1 + io]);
  f32x2 IZp  = mk2(((2 * L <= 99)     ? ws[O_IZ3 + 2 * L]     : 0.f) * CE,
                   ((2 * L + 1 <= 99) ? ws[O_IZ3 + 2 * L + 1] : 0.f) * CE);
  float wk  = ws[O_SC + 0], A00 = ws[O_SC + 1], A01 = ws[O_SC + 2];

  // specials: lanes 60..63 = {0,1,2,3}; lane 51 = 307; lane 52 = 611
  float k0 = 0.f, k1 = 0.f, kx = 0.f;
  if (L == 61) k0 = A01;
  else if (L == 62 || L == 63) k0 = 1.f;
  else if (L == 52) k0 = 0.5f;
  if (L == 60) k1 = A00;
  else if (L == 51) { k1 = 0.5f; kx = 1.f; }
  else if (L == 52) k1 = 1.f;
  const bool isL0 = (L == 0);

  // ---- t = 0: beta = pi * Et[obs0] (packed) ----
  int ob0 = __builtin_amdgcn_readfirstlane(idsb[0]);
  const float* R0 = Etp + (size_t)ob0 * ROWW;
  f32x4 p0 = *(const f32x4*)(pip + L * 16);
  f32x4 p1 = *(const f32x4*)(pip + L * 16 + 4);
  f32x4 p2 = *(const f32x4*)(pip + L * 16 + 8);
  float p3 = pip[L * 16 + 12];
  f32x4 e0 = *(const f32x4*)(R0 + L * 16);
  f32x4 e1 = *(const f32x4*)(R0 + L * 16 + 4);
  f32x4 e2 = *(const f32x4*)(R0 + L * 16 + 8);
  float e3 = R0[L * 16 + 12];

  f32x2 C4 = LO2(p0) * LO2(e0);
  f32x2 C5 = HI2(p0) * HI2(e0);
  f32x2 C6 = LO2(p1) * LO2(e1);
  f32x2 I8 = HI2(p1) * HI2(e1);
  f32x2 I9 = LO2(p2) * LO2(e2);
  f32x2 I10 = HI2(p2) * HI2(e2);
  float spv = p3 * e3;

  // initial md + scan (feed D at t=1); live: Sp, mdo
  float Sp, mdo;
  {
    float sprd0 = ror1(spv);
    float pme = isL0 ? sprd0 : ror1(C6.y);
    f32x2 MD = mk2(pme, C6.x) * IZp;
    mdo = MD.y;
    Sp = scan_plain(MD.x + MD.y);
  }

  int e_acc = 0;

  // ---- single step (prologue only), packed, T dropped ----
#define STEP_BODY(Ra, Rb, Rc, Rd) do { \
    float De = wshr1(Sp); \
    float Do = Sp - mdo; \
    f32x2 Dp = mk2(De, Do); \
    float exc  = ror1(C6.x); \
    float sprd = ror1(spv); \
    float pve = isL0 ? sprd : ror1(C6.y); \
    f32x2 PV = mk2(pve, C6.x); \
    f32x2 T4 = PKF(AV0p, PV, PKF(AV1p, I10, Dp)) * LO2(Ra); \
    f32x2 T5 = C4 * HI2(Ra); \
    f32x2 T6 = C5 * LO2(Rb); \
    f32x2 T8 = PKF(BV0p, PV, BV1p * I10) * HI2(Rb); \
    f32x2 T9 = I8 * LO2(Rc); \
    f32x2 TX = I9 * HI2(Rc); \
    float nsp = fmaf(kx, exc, fmaf(k0, sprd, k1 * spv)) * (Rd); \
    C4 = T4; C5 = T5; C6 = T6; I8 = T8; I9 = T9; I10 = TX; spv = nsp; \
    float sprdn = ror1(spv); \
    float pmn = isL0 ? sprdn : ror1(C6.y); \
    f32x2 MD = mk2(pmn, C6.x) * IZp; \
    mdo = MD.y; \
    Sp = scan_plain(MD.x + MD.y); \
  } while (0)

  // ---- fused 2 steps, packed, T dropped; S-scans interleaved ----
#define FUSE2P(R1a, R1b, R1c, R1d, R2a, R2b, R2c, R2d) do { \
    /* step a */ \
    float De = wshr1(Sp); \
    float Do = Sp - mdo; \
    f32x2 Dp = mk2(De, Do); \
    float exc1  = ror1(C6.x); \
    float sprd1 = ror1(spv); \
    float pve1 = isL0 ? sprd1 : ror1(C6.y); \
    f32x2 PV1 = mk2(pve1, C6.x); \
    f32x2 A4 = PKF(AV0p, PV1, PKF(AV1p, I10, Dp)) * LO2(R1a); \
    f32x2 A5 = C4 * HI2(R1a); \
    f32x2 A6 = C5 * LO2(R1b); \
    f32x2 A8 = PKF(BV0p, PV1, BV1p * I10) * HI2(R1b); \
    f32x2 A9 = I8 * LO2(R1c); \
    f32x2 AX = I9 * HI2(R1c); \
    float asp = fmaf(kx, exc1, fmaf(k0, sprd1, k1 * spv)) * (R1d); \
    /* step b scan-free parts */ \
    f32x2 B5 = A4 * HI2(R2a); \
    f32x2 B6 = A5 * LO2(R2b); \
    f32x2 B9 = A8 * LO2(R2c); \
    f32x2 BX = A9 * HI2(R2c); \
    float exc2  = ror1(A6.x); \
    float sprd2 = ror1(asp); \
    float bsp = fmaf(kx, exc2, fmaf(k0, sprd2, k1 * asp)) * (R2d); \
    float pve2 = isL0 ? sprd2 : ror1(A6.y); \
    f32x2 PV2 = mk2(pve2, A6.x); \
    f32x2 B8 = PKF(BV0p, PV2, BV1p * AX) * HI2(R2b); \
    f32x2 MD1 = PV2 * IZp; \
    float sprd3 = ror1(bsp); \
    float pm3 = isL0 ? sprd3 : ror1(B6.y); \
    f32x2 MD2 = mk2(pm3, B6.x) * IZp; \
    /* interleaved full S-scans */ \
    float Sa = MD1.x + MD1.y; \
    float Sb = MD2.x + MD2.y; \
    Sa += DPPF(Sa, 0x111, 0xf); Sb += DPPF(Sb, 0x111, 0xf); \
    Sa += DPPF(Sa, 0x112, 0xf); Sb += DPPF(Sb, 0x112, 0xf); \
    Sa += DPPF(Sa, 0x114, 0xf); Sb += DPPF(Sb, 0x114, 0xf); \
    Sa += DPPF(Sa, 0x118, 0xf); Sb += DPPF(Sb, 0x118, 0xf); \
    Sa += DPPF(Sa, 0x142, 0xa); Sb += DPPF(Sb, 0x142, 0xa); \
    Sa += DPPF(Sa, 0x143, 0xc); Sb += DPPF(Sb, 0x143, 0xc); \
    /* step b scan-dependent tail */ \
    float De2 = wshr1(Sa); \
    float Do2 = Sa - MD1.y; \
    f32x2 D2p = mk2(De2, Do2); \
    f32x2 B4 = PKF(AV0p, PV2, PKF(AV1p, AX, D2p)) * LO2(R2a); \
    /* commit */ \
    C4 = B4; C5 = B5; C6 = B6; I8 = B8; I9 = B9; I10 = BX; spv = bsp; \
    Sp = Sb; mdo = MD2.y; \
  } while (0)

#define RESCALE() do { \
    f32x2 Psum = ((C4 + C5) + (C6 + I8)) + (I9 + I10); \
    float prr = (Psum.x + Psum.y) + spv; \
    float ssum = rdl(scan_plain(prr), 63); \
    int exq = ((__float_as_int(ssum) >> 23) & 255) - 127; \
    e_acc += exq; \
    float scq = __int_as_float((127 - exq) << 23); \
    f32x2 SC = mk2(scq, scq); \
    C4 *= SC; C5 *= SC; C6 *= SC; I8 *= SC; I9 *= SC; I10 *= SC; \
    spv *= scq; \
    mdo *= scq; Sp *= scq; \
  } while (0)

  // ---- asm load primitives (r8-proven, verbatim) ----
#define GLD4(dst, base, off) \
  asm volatile("global_load_dwordx4 %0, %1, %2 offset:" #off \
               : "=v"(dst) : "v"(voff), "s"(base))
#define GLD1(dst, base, off) \
  asm volatile("global_load_dword %0, %1, %2 offset:" #off \
               : "=v"(dst) : "v"(voff), "s"(base))
#define GLD2(dst, base, vo, off) \
  asm volatile("global_load_dwordx2 %0, %1, %2 offset:" #off \
               : "=v"(dst) : "v"(vo), "s"(base))

#define LOADROW(P, obsv) do { \
    unsigned int _oc = (unsigned int)__builtin_amdgcn_readfirstlane(obsv); \
    unsigned long long _ba = Et64 + ((unsigned long long)_oc << 12); \
    GLD4(P##0, _ba, 0); \
    GLD4(P##1, _ba, 16); \
    GLD4(P##2, _ba, 32); \
    GLD1(P##3, _ba, 48); \
  } while (0)

#define LOADOBS(O, tstart) do { \
    int _ts = (tstart); if (_ts > TLEN - 6) _ts = TLEN - 6; \
    int _vo = _ts * 4; \
    GLD2(O##0, ids64, _vo, 0); \
    GLD2(O##1, ids64, _vo, 8); \
    GLD2(O##2, ids64, _vo, 16); \
  } while (0)

  // ---- prologue: t = 1..7 synchronous ----
  for (int t = 1; t <= 7; ++t) {
    int obp = idsb[t];
    const float* Rx = Etp + (size_t)__builtin_amdgcn_readfirstlane(obp) * ROWW;
    f32x4 P0 = *(const f32x4*)(Rx + L * 16);
    f32x4 P1 = *(const f32x4*)(Rx + L * 16 + 4);
    f32x4 P2 = *(const f32x4*)(Rx + L * 16 + 8);
    float P3 = Rx[L * 16 + 12];
    STEP_BODY(P0, P1, P2, P3);
  }
  RESCALE();

  // ---- pipeline buffers (r8 naming, verbatim) ----
  f32x4 Ar00, Ar01, Ar02; float Ar03;
  f32x4 Ar10, Ar11, Ar12; float Ar13;
  f32x4 Ar20, Ar21, Ar22; float Ar23;
  f32x4 Ar30, Ar31, Ar32; float Ar33;
  f32x4 Ar40, Ar41, Ar42; float Ar43;
  f32x4 Ar50, Ar51, Ar52; float Ar53;
  f32x4 Br00, Br01, Br02; float Br03;
  f32x4 Br10, Br11, Br12; float Br13;
  f32x4 Br20, Br21, Br22; float Br23;
  f32x4 Br30, Br31, Br32; float Br33;
  f32x4 Br40, Br41, Br42; float Br43;
  f32x4 Br50, Br51, Br52; float Br53;
  i32x2 OA0, OA1, OA2, OB0, OB1, OB2;

  LOADOBS(OA, 8);
  asm volatile("s_waitcnt vmcnt(0)" ::: "memory");
  __builtin_amdgcn_sched_barrier(0);
  LOADROW(Ar0, OA0.x);
  LOADROW(Ar1, OA0.y);
  LOADROW(Ar2, OA1.x);
  LOADROW(Ar3, OA1.y);
  LOADROW(Ar4, OA2.x);
  LOADROW(Ar5, OA2.y);
  LOADOBS(OB, 14);

#define ITER(C, OC, N, ON, gexp) do { \
    asm volatile("s_waitcnt vmcnt(0)" ::: "memory"); \
    __builtin_amdgcn_sched_barrier(0); \
    LOADROW(N##r0, (OC##0).x); \
    LOADROW(N##r1, (OC##0).y); \
    LOADROW(N##r2, (OC##1).x); \
    LOADROW(N##r3, (OC##1).y); \
    LOADROW(N##r4, (OC##2).x); \
    LOADROW(N##r5, (OC##2).y); \
    LOADOBS(ON, 8 + 6 * ((gexp) + 2)); \
    FUSE2P(C##r00, C##r01, C##r02, C##r03, C##r10, C##r11, C##r12, C##r13); \
    FUSE2P(C##r20, C##r21, C##r22, C##r23, C##r30, C##r31, C##r32, C##r33); \
    FUSE2P(C##r40, C##r41, C##r42, C##r43, C##r50, C##r51, C##r52, C##r53); \
  } while (0)

  // 340 groups of 6 steps: t = 8 .. 2047; rescale every 12 steps
  for (int g = 0; g < 340; g += 2) {
    ITER(A, OB, B, OA, g);
    ITER(B, OA, A, OB, g + 1);
    RESCALE();
  }

  // ---- final: ll = e_acc*ln2 + log(sum beta_final) ----
  f32x2 Psum = ((C4 + C5) + (C6 + I8)) + (I9 + I10);
  float prr = (Psum.x + Psum.y) + spv;
  float ssum_f = rdl(scan_plain(prr), 63);
  double ll = (double)e_acc * 0.6931471805599453 + (double)logf(ssum_f);
  if (L == 0) out[b] = (float)ll;

#undef STEP_BODY
#undef FUSE2P
#undef RESCALE
#undef GLD4
#undef GLD1
#undef GLD2
#undef LOADROW
#undef LOADOBS
#undef ITER
}

// ---------------- launcher ----------------
extern "C" void kernel_launch(void* const* d_in, const int* in_sizes, int n_in,
                              void* d_out, int out_size, void* d_ws, size_t ws_size,
                              hipStream_t stream) {
  const int*   ids = (const int*)d_in[0];
  const float* w   = (const float*)d_in[1];
  const float* ek  = (const float*)d_in[2];
  const float* ik  = (const float*)d_in[3];
  float* ws  = (float*)d_ws;
  float* out = (float*)d_out;

  k_prep<<<1, 128, 0, stream>>>(w, ws);
  k_zr  <<<NECOL, 256, 0, stream>>>(ws);
  k_pi  <<<1, 640, 0, stream>>>(ik, ws);
  k_et  <<<NS, 64, 0, stream>>>(ek, ws);
  k_main<<<BATCH, 64, 0, stream>>>(ids, ws, out);
}

// Round 22
// 259.781 us; speedup vs baseline: 4.5359x; 1.0017x over previous
//
#include <hip/hip_runtime.h>
#include <math.h>

// ---------------- problem constants ----------------
#define NS 612
#define NECOL 216
#define BATCH 32
#define TLEN 2048
#define ROWW 1024                // floats per permuted emission row (4 KB)
#define CE 2.7182818284590452f

// ---------------- ws layout (float offsets) ----------------
#define O_AV0 0
#define O_AV1 128
#define O_BV0 256
#define O_BV1 384
#define O_IZ3 512
#define O_SC  640                // [0]=wk [1]=A00 [2]=A01
#define O_PIP 768                // [1024] permuted softmax(init)
#define O_ET  2048               // [216*1024] permuted E^T rows

typedef float f32x4 __attribute__((ext_vector_type(4)));
typedef float f32x2 __attribute__((ext_vector_type(2)));
typedef int   i32x2 __attribute__((ext_vector_type(2)));

// PACKED slot map (r17-verified): lane L holds pair i=2L,2L+1, 13 floats at
// row+L*64B: f0,f1=c4e,c4o f2,f3=c5e,c5o f4,f5=c6e,c6o f6,f7=i8e,i8o
// f8,f9=i9e,i9o f10,f11=i10e,i10o f12=special-Et
// specials: {0,1,2,3}->lanes 60..63, {307}->lane 51, {611}->lane 52
__device__ __forceinline__ int eslot(int s) {
  if (s >= 4 && s <= 306)  { int i = (s - 4) / 3,  r = (s - 4) % 3;
    return (i >> 1) * 16 + 2 * r + (i & 1); }
  if (s >= 308 && s <= 610){ int i = (s - 308) / 3, r = (s - 308) % 3;
    return (i >> 1) * 16 + 6 + 2 * r + (i & 1); }
  if (s <= 3)   return (60 + s) * 16 + 12;
  if (s == 307) return 51 * 16 + 12;
  return 52 * 16 + 12;   // s == 611
}

// ---------------- DPP / packed helpers ----------------
#define DPPF(x, ctrl, rm) __int_as_float(__builtin_amdgcn_update_dpp(0, __float_as_int(x), (ctrl), (rm), 0xf, true))
#define LO2(v) __builtin_shufflevector((v), (v), 0, 1)
#define HI2(v) __builtin_shufflevector((v), (v), 2, 3)
#define PKF(a, b, c) __builtin_elementwise_fma((a), (b), (c))

__device__ __forceinline__ f32x2 mk2(float a, float b) { f32x2 r; r.x = a; r.y = b; return r; }

__device__ __forceinline__ float scan_plain(float x) {
  x += DPPF(x, 0x111, 0xf);
  x += DPPF(x, 0x112, 0xf);
  x += DPPF(x, 0x114, 0xf);
  x += DPPF(x, 0x118, 0xf);
  x += DPPF(x, 0x142, 0xa);
  x += DPPF(x, 0x143, 0xc);
  return x;
}
__device__ __forceinline__ float wshr1(float x) { return DPPF(x, 0x138, 0xf); }   // dst[l]=src[l-1], dst[0]=0
__device__ __forceinline__ float ror1(float x)  { return DPPF(x, 0x13C, 0xf); }   // dst[l]=src[l-1], dst[0]=src[63]
__device__ __forceinline__ float rdl(float x, int l) {
  return __int_as_float(__builtin_amdgcn_readlane(__float_as_int(x), l));
}

// ---------------- prep kernels (math unchanged, verified) ----------------
__global__ void k_prep(const float* __restrict__ w, float* __restrict__ ws) {
  __shared__ float Gs[101];
  int tid = threadIdx.x;                  // 128
  float wk = w[304];
  if (tid >= 1 && tid <= 100) {
    float p = wk;
    for (int k = 0; k < tid; ++k) p *= wk;
    Gs[tid] = expf(1.f - p);
  }
  if (tid == 0) {
    Gs[0] = 0.f;
    ws[O_SC + 0] = wk;
    float Z0 = expf(1.f - w[0]) + expf(w[0]);
    ws[O_SC + 1] = expf(1.f - w[0]) / Z0;
    ws[O_SC + 2] = expf(w[0]) / Z0;
  }
  __syncthreads();
  if (tid <= 100) {
    float em = expf(w[tid < 100 ? 1 + tid : 202]);
    float ei = expf(w[101 + tid]);
    float z = em + ei;
    for (int d = 1; d <= 100 - tid; ++d) z += Gs[d];
    float ex = expf(w[203 + tid]);
    float es = expf(1.f - w[203 + tid]);
    float z310 = ex + es;
    ws[O_AV0 + tid] = em / z;
    ws[O_BV0 + tid] = ei / z;
    ws[O_AV1 + tid] = ex / z310;
    ws[O_BV1 + tid] = es / z310;
    ws[O_IZ3 + tid] = 1.f / z;
  }
}

__global__ void k_zr(float* __restrict__ ws) {
  float* row = ws + O_ET + (size_t)blockIdx.x * ROWW;
  for (int i = threadIdx.x; i < ROWW; i += 256) row[i] = 0.f;
}

__global__ void k_et(const float* __restrict__ ek, float* __restrict__ ws) {
  float* Etp = ws + O_ET;
  int s = blockIdx.x;
  int lane = threadIdx.x;                 // 64
  int sl = eslot(s);
  float x[4]; float m = -1e30f;
  #pragma unroll
  for (int k = 0; k < 4; ++k) {
    int c = lane + 64 * k;
    x[k] = (c < NECOL) ? ek[s * NECOL + c] : -1e30f;
    m = fmaxf(m, x[k]);
  }
  #pragma unroll
  for (int o = 32; o; o >>= 1) m = fmaxf(m, __shfl_xor(m, o, 64));
  float e[4]; float sum = 0.f;
  #pragma unroll
  for (int k = 0; k < 4; ++k) {
    int c = lane + 64 * k;
    e[k] = (c < NECOL) ? expf(x[k] - m) : 0.f;
    sum += e[k];
  }
  #pragma unroll
  for (int o = 32; o; o >>= 1) sum += __shfl_xor(sum, o, 64);
  float inv = 1.f / sum;
  #pragma unroll
  for (int k = 0; k < 4; ++k) {
    int c = lane + 64 * k;
    if (c < NECOL) Etp[(size_t)c * ROWW + sl] = e[k] * inv;
  }
}

__global__ void k_pi(const float* __restrict__ ik, float* __restrict__ ws) {
  float* pip = ws + O_PIP;
  __shared__ float wm[10], wsm[10];
  int tid = threadIdx.x;                  // 640
  for (int i = tid; i < ROWW; i += 640) pip[i] = 0.f;
  __syncthreads();
  int lane = tid & 63, wid = tid >> 6;
  float x = (tid < NS) ? ik[tid] : -1e30f;
  float m = x;
  #pragma unroll
  for (int o = 32; o; o >>= 1) m = fmaxf(m, __shfl_xor(m, o, 64));
  if (lane == 0) wm[wid] = m;
  __syncthreads();
  float mm = wm[0];
  #pragma unroll
  for (int k = 1; k < 10; ++k) mm = fmaxf(mm, wm[k]);
  float e = (tid < NS) ? expf(x - mm) : 0.f;
  float sacc = e;
  #pragma unroll
  for (int o = 32; o; o >>= 1) sacc += __shfl_xor(sacc, o, 64);
  if (lane == 0) wsm[wid] = sacc;
  __syncthreads();
  float ss = 0.f;
  #pragma unroll
  for (int k = 0; k < 10; ++k) ss += wsm[k];
  if (tid < NS) pip[eslot(tid)] = e / ss;
}

// ---------------- main: one WAVE per sequence; packed-f32, T-chain dropped --
// r19 (verified 244us, absmax 0): De = wshr1(S), Do = S - mdo
// (2nd-order exact in wk; rel err <= wk^2)
__global__ __launch_bounds__(64, 1) void k_main(const int* __restrict__ ids,
                                                const float* __restrict__ ws,
                                                float* __restrict__ out) {
  const int L = threadIdx.x, b = blockIdx.x;
  const int* idsb = ids + b * TLEN;
  const float* Etp = ws + O_ET;
  const float* pip = ws + O_PIP;
  const unsigned long long Et64 = (unsigned long long)Etp;
  const unsigned long long ids64 = (unsigned long long)idsb;
  const int voff = L << 6;

  // per-lane coefficient PAIRS
  int ie = 2 * L;     if (ie > 100) ie = 100;
  int io = 2 * L + 1; if (io > 100) io = 100;
  f32x2 AV0p = mk2(ws[O_AV0 + ie], ws[O_AV0 + io]);
  f32x2 AV1p = mk2(ws[O_AV1 + ie], ws[O_AV1 + io]);
  f32x2 BV0p = mk2(ws[O_BV0 + ie], ws[O_BV0 + io]);
  f32x2 BV1p = mk2(ws[O_BV1 + ie], ws[O_BV1 + io]);
  f32x2 IZp  = mk2(((2 * L <= 99)     ? ws[O_IZ3 + 2 * L]     : 0.f) * CE,
                   ((2 * L + 1 <= 99) ? ws[O_IZ3 + 2 * L + 1] : 0.f) * CE);
  float wk  = ws[O_SC + 0], A00 = ws[O_SC + 1], A01 = ws[O_SC + 2];

  // specials: lanes 60..63 = {0,1,2,3}; lane 51 = 307; lane 52 = 611
  float k0 = 0.f, k1 = 0.f, kx = 0.f;
  if (L == 61) k0 = A01;
  else if (L == 62 || L == 63) k0 = 1.f;
  else if (L == 52) k0 = 0.5f;
  if (L == 60) k1 = A00;
  else if (L == 51) { k1 = 0.5f; kx = 1.f; }
  else if (L == 52) k1 = 1.f;
  const bool isL0 = (L == 0);

  // ---- t = 0: beta = pi * Et[obs0] (packed) ----
  int ob0 = __builtin_amdgcn_readfirstlane(idsb[0]);
  const float* R0 = Etp + (size_t)ob0 * ROWW;
  f32x4 p0 = *(const f32x4*)(pip + L * 16);
  f32x4 p1 = *(const f32x4*)(pip + L * 16 + 4);
  f32x4 p2 = *(const f32x4*)(pip + L * 16 + 8);
  float p3 = pip[L * 16 + 12];
  f32x4 e0 = *(const f32x4*)(R0 + L * 16);
  f32x4 e1 = *(const f32x4*)(R0 + L * 16 + 4);
  f32x4 e2 = *(const f32x4*)(R0 + L * 16 + 8);
  float e3 = R0[L * 16 + 12];

  f32x2 C4 = LO2(p0) * LO2(e0);
  f32x2 C5 = HI2(p0) * HI2(e0);
  f32x2 C6 = LO2(p1) * LO2(e1);
  f32x2 I8 = HI2(p1) * HI2(e1);
  f32x2 I9 = LO2(p2) * LO2(e2);
  f32x2 I10 = HI2(p2) * HI2(e2);
  float spv = p3 * e3;

  // initial md + scan (feed D at t=1); live: Sp, mdo
  float Sp, mdo;
  {
    float sprd0 = ror1(spv);
    float pme = isL0 ? sprd0 : ror1(C6.y);
    f32x2 MD = mk2(pme, C6.x) * IZp;
    mdo = MD.y;
    Sp = scan_plain(MD.x + MD.y);
  }

  int e_acc = 0;

  // ---- single step (prologue only), packed, T dropped ----
#define STEP_BODY(Ra, Rb, Rc, Rd) do { \
    float De = wshr1(Sp); \
    float Do = Sp - mdo; \
    f32x2 Dp = mk2(De, Do); \
    float exc  = ror1(C6.x); \
    float sprd = ror1(spv); \
    float pve = isL0 ? sprd : ror1(C6.y); \
    f32x2 PV = mk2(pve, C6.x); \
    f32x2 T4 = PKF(AV0p, PV, PKF(AV1p, I10, Dp)) * LO2(Ra); \
    f32x2 T5 = C4 * HI2(Ra); \
    f32x2 T6 = C5 * LO2(Rb); \
    f32x2 T8 = PKF(BV0p, PV, BV1p * I10) * HI2(Rb); \
    f32x2 T9 = I8 * LO2(Rc); \
    f32x2 TX = I9 * HI2(Rc); \
    float nsp = fmaf(kx, exc, fmaf(k0, sprd, k1 * spv)) * (Rd); \
    C4 = T4; C5 = T5; C6 = T6; I8 = T8; I9 = T9; I10 = TX; spv = nsp; \
    float sprdn = ror1(spv); \
    float pmn = isL0 ? sprdn : ror1(C6.y); \
    f32x2 MD = mk2(pmn, C6.x) * IZp; \
    mdo = MD.y; \
    Sp = scan_plain(MD.x + MD.y); \
  } while (0)

  // ---- fused 2 steps, packed, T dropped; S-scans interleaved ----
#define FUSE2P(R1a, R1b, R1c, R1d, R2a, R2b, R2c, R2d) do { \
    /* step a */ \
    float De = wshr1(Sp); \
    float Do = Sp - mdo; \
    f32x2 Dp = mk2(De, Do); \
    float exc1  = ror1(C6.x); \
    float sprd1 = ror1(spv); \
    float pve1 = isL0 ? sprd1 : ror1(C6.y); \
    f32x2 PV1 = mk2(pve1, C6.x); \
    f32x2 A4 = PKF(AV0p, PV1, PKF(AV1p, I10, Dp)) * LO2(R1a); \
    f32x2 A5 = C4 * HI2(R1a); \
    f32x2 A6 = C5 * LO2(R1b); \
    f32x2 A8 = PKF(BV0p, PV1, BV1p * I10) * HI2(R1b); \
    f32x2 A9 = I8 * LO2(R1c); \
    f32x2 AX = I9 * HI2(R1c); \
    float asp = fmaf(kx, exc1, fmaf(k0, sprd1, k1 * spv)) * (R1d); \
    /* step b scan-free parts */ \
    f32x2 B5 = A4 * HI2(R2a); \
    f32x2 B6 = A5 * LO2(R2b); \
    f32x2 B9 = A8 * LO2(R2c); \
    f32x2 BX = A9 * HI2(R2c); \
    float exc2  = ror1(A6.x); \
    float sprd2 = ror1(asp); \
    float bsp = fmaf(kx, exc2, fmaf(k0, sprd2, k1 * asp)) * (R2d); \
    float pve2 = isL0 ? sprd2 : ror1(A6.y); \
    f32x2 PV2 = mk2(pve2, A6.x); \
    f32x2 B8 = PKF(BV0p, PV2, BV1p * AX) * HI2(R2b); \
    f32x2 MD1 = PV2 * IZp; \
    float sprd3 = ror1(bsp); \
    float pm3 = isL0 ? sprd3 : ror1(B6.y); \
    f32x2 MD2 = mk2(pm3, B6.x) * IZp; \
    /* interleaved full S-scans */ \
    float Sa = MD1.x + MD1.y; \
    float Sb = MD2.x + MD2.y; \
    Sa += DPPF(Sa, 0x111, 0xf); Sb += DPPF(Sb, 0x111, 0xf); \
    Sa += DPPF(Sa, 0x112, 0xf); Sb += DPPF(Sb, 0x112, 0xf); \
    Sa += DPPF(Sa, 0x114, 0xf); Sb += DPPF(Sb, 0x114, 0xf); \
    Sa += DPPF(Sa, 0x118, 0xf); Sb += DPPF(Sb, 0x118, 0xf); \
    Sa += DPPF(Sa, 0x142, 0xa); Sb += DPPF(Sb, 0x142, 0xa); \
    Sa += DPPF(Sa, 0x143, 0xc); Sb += DPPF(Sb, 0x143, 0xc); \
    /* step b scan-dependent tail */ \
    float De2 = wshr1(Sa); \
    float Do2 = Sa - MD1.y; \
    f32x2 D2p = mk2(De2, Do2); \
    f32x2 B4 = PKF(AV0p, PV2, PKF(AV1p, AX, D2p)) * LO2(R2a); \
    /* commit */ \
    C4 = B4; C5 = B5; C6 = B6; I8 = B8; I9 = B9; I10 = BX; spv = bsp; \
    Sp = Sb; mdo = MD2.y; \
  } while (0)

#define RESCALE() do { \
    f32x2 Psum = ((C4 + C5) + (C6 + I8)) + (I9 + I10); \
    float prr = (Psum.x + Psum.y) + spv; \
    float ssum = rdl(scan_plain(prr), 63); \
    int exq = ((__float_as_int(ssum) >> 23) & 255) - 127; \
    e_acc += exq; \
    float scq = __int_as_float((127 - exq) << 23); \
    f32x2 SC = mk2(scq, scq); \
    C4 *= SC; C5 *= SC; C6 *= SC; I8 *= SC; I9 *= SC; I10 *= SC; \
    spv *= scq; \
    mdo *= scq; Sp *= scq; \
  } while (0)

  // ---- asm load primitives (r8-proven, verbatim) ----
#define GLD4(dst, base, off) \
  asm volatile("global_load_dwordx4 %0, %1, %2 offset:" #off \
               : "=v"(dst) : "v"(voff), "s"(base))
#define GLD1(dst, base, off) \
  asm volatile("global_load_dword %0, %1, %2 offset:" #off \
               : "=v"(dst) : "v"(voff), "s"(base))
#define GLD2(dst, base, vo, off) \
  asm volatile("global_load_dwordx2 %0, %1, %2 offset:" #off \
               : "=v"(dst) : "v"(vo), "s"(base))

#define LOADROW(P, obsv) do { \
    unsigned int _oc = (unsigned int)__builtin_amdgcn_readfirstlane(obsv); \
    unsigned long long _ba = Et64 + ((unsigned long long)_oc << 12); \
    GLD4(P##0, _ba, 0); \
    GLD4(P##1, _ba, 16); \
    GLD4(P##2, _ba, 32); \
    GLD1(P##3, _ba, 48); \
  } while (0)

#define LOADOBS(O, tstart) do { \
    int _ts = (tstart); if (_ts > TLEN - 6) _ts = TLEN - 6; \
    int _vo = _ts * 4; \
    GLD2(O##0, ids64, _vo, 0); \
    GLD2(O##1, ids64, _vo, 8); \
    GLD2(O##2, ids64, _vo, 16); \
  } while (0)

  // ---- prologue: t = 1..7 synchronous ----
  for (int t = 1; t <= 7; ++t) {
    int obp = idsb[t];
    const float* Rx = Etp + (size_t)__builtin_amdgcn_readfirstlane(obp) * ROWW;
    f32x4 P0 = *(const f32x4*)(Rx + L * 16);
    f32x4 P1 = *(const f32x4*)(Rx + L * 16 + 4);
    f32x4 P2 = *(const f32x4*)(Rx + L * 16 + 8);
    float P3 = Rx[L * 16 + 12];
    STEP_BODY(P0, P1, P2, P3);
  }
  RESCALE();

  // ---- pipeline buffers (r8 naming, verbatim) ----
  f32x4 Ar00, Ar01, Ar02; float Ar03;
  f32x4 Ar10, Ar11, Ar12; float Ar13;
  f32x4 Ar20, Ar21, Ar22; float Ar23;
  f32x4 Ar30, Ar31, Ar32; float Ar33;
  f32x4 Ar40, Ar41, Ar42; float Ar43;
  f32x4 Ar50, Ar51, Ar52; float Ar53;
  f32x4 Br00, Br01, Br02; float Br03;
  f32x4 Br10, Br11, Br12; float Br13;
  f32x4 Br20, Br21, Br22; float Br23;
  f32x4 Br30, Br31, Br32; float Br33;
  f32x4 Br40, Br41, Br42; float Br43;
  f32x4 Br50, Br51, Br52; float Br53;
  i32x2 OA0, OA1, OA2, OB0, OB1, OB2;

  LOADOBS(OA, 8);
  asm volatile("s_waitcnt vmcnt(0)" ::: "memory");
  __builtin_amdgcn_sched_barrier(0);
  LOADROW(Ar0, OA0.x);
  LOADROW(Ar1, OA0.y);
  LOADROW(Ar2, OA1.x);
  LOADROW(Ar3, OA1.y);
  LOADROW(Ar4, OA2.x);
  LOADROW(Ar5, OA2.y);
  LOADOBS(OB, 14);

#define ITER(C, OC, N, ON, gexp) do { \
    asm volatile("s_waitcnt vmcnt(0)" ::: "memory"); \
    __builtin_amdgcn_sched_barrier(0); \
    LOADROW(N##r0, (OC##0).x); \
    LOADROW(N##r1, (OC##0).y); \
    LOADROW(N##r2, (OC##1).x); \
    LOADROW(N##r3, (OC##1).y); \
    LOADROW(N##r4, (OC##2).x); \
    LOADROW(N##r5, (OC##2).y); \
    LOADOBS(ON, 8 + 6 * ((gexp) + 2)); \
    FUSE2P(C##r00, C##r01, C##r02, C##r03, C##r10, C##r11, C##r12, C##r13); \
    FUSE2P(C##r20, C##r21, C##r22, C##r23, C##r30, C##r31, C##r32, C##r33); \
    FUSE2P(C##r40, C##r41, C##r42, C##r43, C##r50, C##r51, C##r52, C##r53); \
  } while (0)

  // 340 groups of 6 steps: t = 8 .. 2047; rescale every 12 steps
  for (int g = 0; g < 340; g += 2) {
    ITER(A, OB, B, OA, g);
    ITER(B, OA, A, OB, g + 1);
    RESCALE();
  }

  // ---- final: ll = e_acc*ln2 + log(sum beta_final) ----
  f32x2 Psum = ((C4 + C5) + (C6 + I8)) + (I9 + I10);
  float prr = (Psum.x + Psum.y) + spv;
  float ssum_f = rdl(scan_plain(prr), 63);
  double ll = (double)e_acc * 0.6931471805599453 + (double)logf(ssum_f);
  if (L == 0) out[b] = (float)ll;

#undef STEP_BODY
#undef FUSE2P
#undef RESCALE
#undef GLD4
#undef GLD1
#undef GLD2
#undef LOADROW
#undef LOADOBS
#undef ITER
}

// ---------------- launcher ----------------
extern "C" void kernel_launch(void* const* d_in, const int* in_sizes, int n_in,
                              void* d_out, int out_size, void* d_ws, size_t ws_size,
                              hipStream_t stream) {
  const int*   ids = (const int*)d_in[0];
  const float* w   = (const float*)d_in[1];
  const float* ek  = (const float*)d_in[2];
  const float* ik  = (const float*)d_in[3];
  float* ws  = (float*)d_ws;
  float* out = (float*)d_out;

  k_prep<<<1, 128, 0, stream>>>(w, ws);
  k_zr  <<<NECOL, 256, 0, stream>>>(ws);
  k_pi  <<<1, 640, 0, stream>>>(ik, ws);
  k_et  <<<NS, 64, 0, stream>>>(ek, ws);
  k_main<<<BATCH, 64, 0, stream>>>(ids, ws, out);
}